// Round 1
// baseline (702.059 us; speedup 1.0000x reference)
//
#include <hip/hip_runtime.h>

#define EPSV 1e-5f
#define GRID_GEMM 1563
#define GRID_MIX  3125
#define GRID_ELT  2048

__device__ __forceinline__ float frelu(float x) { return fmaxf(x, 0.f); }

// ---------------------------------------------------------------------------
// wp2wT[g][a] = sum_c Wp2[a][c] * Ww[c][g]   (stored transposed, 8 x 64)
__global__ __launch_bounds__(64) void wp2w_k(const float* __restrict__ Wp2,
                                             const float* __restrict__ Ww,
                                             float* __restrict__ wp2wT)
{
  const int a = threadIdx.x;
  float acc[8] = {0,0,0,0,0,0,0,0};
  for (int c = 0; c < 64; ++c) {
    const float wv = Wp2[a*64 + c];
#pragma unroll
    for (int g = 0; g < 8; ++g) acc[g] = fmaf(wv, Ww[c*8 + g], acc[g]);
  }
#pragma unroll
  for (int g = 0; g < 8; ++g) wp2wT[g*64 + a] = acc[g];
}

// ---------------------------------------------------------------------------
// out[N,64] = preop(in) @ W ; MODE0: no preop, emit stats partials
// MODE1: preop = relu(bn) via ss, also out2[N,8] = preop(in)@Ww, no partials
// MODE2: preop = relu(bn) via ss, emit stats partials
template<int MODE>
__global__ __launch_bounds__(256) void gemm64_k(
    const float* __restrict__ in, const float* __restrict__ W,
    const float* __restrict__ Ww, const float* __restrict__ ss,
    float* __restrict__ out, float* __restrict__ outw,
    float* __restrict__ partials, int N)
{
  __shared__ float lds[4096 + 512 + 4*1280 + 512];
  float* const Wl  = lds;
  float* const Wwl = lds + 4096;
  const int t = threadIdx.x, lane = t & 63, w = t >> 6;
  float* const xw  = lds + 4608 + w*1280;   // [64 d][20] per-wave tile (pad 20)
  float* const red = lds + 4608 + 4*1280;   // [4][128]

  for (int idx = t; idx < 4096; idx += 256) Wl[idx] = W[idx];
  if (MODE == 1) { for (int idx = t; idx < 512; idx += 256) Wwl[idx] = Ww[idx]; }
  float sc = 1.f, sh = 0.f;
  if (MODE != 0) { sc = ss[lane]; sh = ss[64 + lane]; }
  __syncthreads();

  float ssum = 0.f, sq = 0.f;
  const int ntiles = (N + 15) >> 4;
  for (int tile = blockIdx.x*4 + w; tile < ntiles; tile += gridDim.x*4) {
    const int r0 = tile << 4;
    const int rmax = min(16, N - r0);
#pragma unroll
    for (int rr = 0; rr < 16; ++rr) {
      float val = (rr < rmax) ? in[(size_t)(r0 + rr)*64 + lane] : 0.f;
      if (MODE != 0) val = frelu(fmaf(val, sc, sh));
      xw[lane*20 + rr] = val;                       // transposed store, 2-way ok
    }
    float acc[16];
#pragma unroll
    for (int rr = 0; rr < 16; ++rr) acc[rr] = 0.f;
#pragma unroll 4
    for (int d = 0; d < 64; ++d) {
      const float wv = Wl[d*64 + lane];
      const float4 xa = *(const float4*)(xw + d*20);
      const float4 xb = *(const float4*)(xw + d*20 + 4);
      const float4 xc = *(const float4*)(xw + d*20 + 8);
      const float4 xd = *(const float4*)(xw + d*20 + 12);
      acc[0]  = fmaf(xa.x, wv, acc[0]);  acc[1]  = fmaf(xa.y, wv, acc[1]);
      acc[2]  = fmaf(xa.z, wv, acc[2]);  acc[3]  = fmaf(xa.w, wv, acc[3]);
      acc[4]  = fmaf(xb.x, wv, acc[4]);  acc[5]  = fmaf(xb.y, wv, acc[5]);
      acc[6]  = fmaf(xb.z, wv, acc[6]);  acc[7]  = fmaf(xb.w, wv, acc[7]);
      acc[8]  = fmaf(xc.x, wv, acc[8]);  acc[9]  = fmaf(xc.y, wv, acc[9]);
      acc[10] = fmaf(xc.z, wv, acc[10]); acc[11] = fmaf(xc.w, wv, acc[11]);
      acc[12] = fmaf(xd.x, wv, acc[12]); acc[13] = fmaf(xd.y, wv, acc[13]);
      acc[14] = fmaf(xd.z, wv, acc[14]); acc[15] = fmaf(xd.w, wv, acc[15]);
    }
#pragma unroll
    for (int rr = 0; rr < 16; ++rr) {
      if (rr < rmax) {
        out[(size_t)(r0 + rr)*64 + lane] = acc[rr];
        if (MODE != 1) { ssum += acc[rr]; sq = fmaf(acc[rr], acc[rr], sq); }
      }
    }
    if (MODE == 1) {
#pragma unroll
      for (int half = 0; half < 2; ++half) {
        const int r = half*8 + (lane >> 3);
        const int g = lane & 7;
        float a2 = 0.f;
#pragma unroll 8
        for (int d = 0; d < 64; ++d) a2 = fmaf(xw[d*20 + r], Wwl[d*8 + g], a2);
        if (r < rmax) outw[(size_t)(r0 + r)*8 + g] = a2;
      }
    }
  }
  if (MODE != 1) {
    __syncthreads();
    red[w*128 + lane] = ssum; red[w*128 + 64 + lane] = sq;
    __syncthreads();
    if (t < 64) {
      const float s = red[t] + red[128+t] + red[256+t] + red[384+t];
      const float q = red[64+t] + red[192+t] + red[320+t] + red[448+t];
      partials[(size_t)blockIdx.x*128 + t]      = s;
      partials[(size_t)blockIdx.x*128 + 64 + t] = q;
    }
  }
}

// ---------------------------------------------------------------------------
__global__ __launch_bounds__(256) void finalize_k(const float* __restrict__ partials,
    int nblk, const float* __restrict__ gamma, const float* __restrict__ beta,
    float* __restrict__ ss, float invN)
{
  __shared__ float red[512];
  const int t = threadIdx.x, c = t & 63, ch = t >> 6;
  float s = 0.f, q = 0.f;
  for (int b = ch; b < nblk; b += 4) {
    s += partials[(size_t)b*128 + c];
    q += partials[(size_t)b*128 + 64 + c];
  }
  red[ch*128 + c] = s; red[ch*128 + 64 + c] = q;
  __syncthreads();
  if (t < 64) {
    const float S = red[t] + red[128+t] + red[256+t] + red[384+t];
    const float Q = red[64+t] + red[192+t] + red[320+t] + red[448+t];
    const float mean = S*invN;
    const float var  = Q*invN - mean*mean;
    const float scale = gamma[t] * rsqrtf(var + EPSV);
    ss[t] = scale; ss[64+t] = beta[t] - mean*scale;
  }
}

// ---------------------------------------------------------------------------
// Wave-per-point mixer. lane roles: Phase A/S/e-part: lane = channel d/c;
// Phase B (energies+softmax): lane = 4*k + gg  (gg covers g = 2gg, 2gg+1)
__global__ __launch_bounds__(256) void mixer_k(
    const float* __restrict__ p, const int* __restrict__ knn,
    const float* __restrict__ v, const float* __restrict__ hw,
    const float* __restrict__ Wp1, const float* __restrict__ Wp2,
    const float* __restrict__ wp2wT, float* __restrict__ mixed,
    float* __restrict__ partials, int N)
{
  __shared__ float lds[12768];
  float* const Wp2T = lds;                  // [64 c][68], 4-chunk XOR swizzle
  float* const wwT  = lds + 4352;           // [8 g][68]
  const int t = threadIdx.x, lane = t & 63, w = t >> 6;
  float* const wb  = lds + 4896 + w*1840;
  float* const e_s = wb;                    // [16 k][68]
  float* const w_s = wb + 1088;             // [16 k][8]
  float* const S_s = wb + 1216;             // [8 g][68]
  int*   const j_s = (int*)(wb + 1760);     // [16]
  float* const pd  = wb + 1776;             // [16] float4 deltas
  float* const red = lds + 4896 + 4*1840;   // [4][128]

  for (int idx = t; idx < 4096; idx += 256) {
    const int d = idx >> 6, c = idx & 63;
    const int dd = d >> 2, r = d & 3, s = (c >> 3) & 3;
    Wp2T[c*68 + ((dd ^ s) << 2) + r] = Wp2[idx];
  }
  for (int idx = t; idx < 512; idx += 256)
    wwT[(idx >> 6)*68 + (idx & 63)] = wp2wT[idx];
  __syncthreads();

  const float w1x = Wp1[lane], w1y = Wp1[64 + lane], w1z = Wp1[128 + lane];
  const int kb = lane >> 2, gg = lane & 3, g8 = lane >> 3;
  const int sxor = g8 & 3;
  float ssum = 0.f, sq = 0.f;
  const int nwaves = gridDim.x * 4;

  for (int i = blockIdx.x*4 + w; i < N; i += nwaves) {
    // ---- P0: lanes 0..15 fetch neighbor idx + relative position
    if (lane < 16) {
      const int j = knn[(size_t)i*16 + lane];
      j_s[lane] = j;
      const float pix = p[(size_t)i*3], piy = p[(size_t)i*3+1], piz = p[(size_t)i*3+2];
      float4 d4;
      d4.x = p[(size_t)j*3]   - pix;
      d4.y = p[(size_t)j*3+1] - piy;
      d4.z = p[(size_t)j*3+2] - piz;
      d4.w = 0.f;
      *(float4*)(pd + lane*4) = d4;
    }
    // ---- Phase A: e'[k] for this lane's channel d
    float ep[16];
#pragma unroll
    for (int k = 0; k < 16; ++k) {
      const float4 d4 = *(const float4*)(pd + k*4);
      ep[k] = frelu(fmaf(d4.x, w1x, fmaf(d4.y, w1y, d4.z*w1z)));
      e_s[k*68 + lane] = ep[k];
    }
    // ---- Phase B: energies for (kb, g=2gg / 2gg+1)
    const int jb = j_s[kb];
    const float2 hw2 = *(const float2*)(hw + (size_t)jb*8 + 2*gg);
    float en0 = hw2.x, en1 = hw2.y;
#pragma unroll
    for (int dd = 0; dd < 16; ++dd) {
      const float4 e4 = *(const float4*)(e_s + kb*68 + dd*4);
      const float4 a0 = *(const float4*)(wwT + (2*gg)*68 + dd*4);
      const float4 a1 = *(const float4*)(wwT + (2*gg+1)*68 + dd*4);
      en0 += e4.x*a0.x + e4.y*a0.y + e4.z*a0.z + e4.w*a0.w;
      en1 += e4.x*a1.x + e4.y*a1.y + e4.z*a1.z + e4.w*a1.w;
    }
    // softmax over k (lanes stride 4)
    float m0 = en0, m1 = en1;
#pragma unroll
    for (int mk = 4; mk < 64; mk <<= 1) {
      m0 = fmaxf(m0, __shfl_xor(m0, mk));
      m1 = fmaxf(m1, __shfl_xor(m1, mk));
    }
    const float p0 = __expf(en0 - m0), p1 = __expf(en1 - m1);
    float s0 = p0, s1 = p1;
#pragma unroll
    for (int mk = 4; mk < 64; mk <<= 1) {
      s0 += __shfl_xor(s0, mk);
      s1 += __shfl_xor(s1, mk);
    }
    float2 wout; wout.x = p0 / s0; wout.y = p1 / s1;
    *(float2*)(w_s + kb*8 + 2*gg) = wout;
    // ---- Phase S: S[g][d=lane] = sum_k w[k][g] * e'[k][d]
    float S[8] = {0,0,0,0,0,0,0,0};
#pragma unroll
    for (int k = 0; k < 16; ++k) {
      const float4 wa = *(const float4*)(w_s + k*8);
      const float4 wc = *(const float4*)(w_s + k*8 + 4);
      const float e = ep[k];
      S[0] = fmaf(wa.x, e, S[0]); S[1] = fmaf(wa.y, e, S[1]);
      S[2] = fmaf(wa.z, e, S[2]); S[3] = fmaf(wa.w, e, S[3]);
      S[4] = fmaf(wc.x, e, S[4]); S[5] = fmaf(wc.y, e, S[5]);
      S[6] = fmaf(wc.z, e, S[6]); S[7] = fmaf(wc.w, e, S[7]);
    }
#pragma unroll
    for (int g = 0; g < 8; ++g) S_s[g*68 + lane] = S[g];
    // ---- vsum: coalesced v gathers
    float acc = 0.f;
#pragma unroll
    for (int k = 0; k < 16; ++k) {
      const int jk = j_s[k];
      const float vv = v[(size_t)jk*64 + lane];
      acc = fmaf(w_s[k*8 + g8], vv, acc);
    }
    // ---- e-part: acc += sum_d S[g(c)][d] * Wp2[d][c]
#pragma unroll
    for (int dd = 0; dd < 16; ++dd) {
      const float4 s4 = *(const float4*)(S_s + g8*68 + dd*4);
      const float4 wp = *(const float4*)(Wp2T + lane*68 + ((dd ^ sxor) << 2));
      acc += s4.x*wp.x + s4.y*wp.y + s4.z*wp.z + s4.w*wp.w;
    }
    mixed[(size_t)i*64 + lane] = acc;
    ssum += acc; sq = fmaf(acc, acc, sq);
  }
  __syncthreads();
  red[w*128 + lane] = ssum; red[w*128 + 64 + lane] = sq;
  __syncthreads();
  if (t < 64) {
    const float s = red[t] + red[128+t] + red[256+t] + red[384+t];
    const float q = red[64+t] + red[192+t] + red[320+t] + red[448+t];
    partials[(size_t)blockIdx.x*128 + t]      = s;
    partials[(size_t)blockIdx.x*128 + 64 + t] = q;
  }
}

// ---------------------------------------------------------------------------
__global__ __launch_bounds__(256) void final_k(const float* __restrict__ y3,
    const float* __restrict__ x, const float* __restrict__ ss,
    float* __restrict__ out, int n4)
{
  __shared__ float sl[128];
  if (threadIdx.x < 128) sl[threadIdx.x] = ss[threadIdx.x];
  __syncthreads();
  for (int idx = blockIdx.x*256 + threadIdx.x; idx < n4; idx += gridDim.x*256) {
    const int cb = (idx & 15) << 2;
    const float4 y  = ((const float4*)y3)[idx];
    const float4 xx = ((const float4*)x)[idx];
    float4 o;
    o.x = frelu(fmaf(y.x, sl[cb],   sl[64+cb])   + xx.x);
    o.y = frelu(fmaf(y.y, sl[cb+1], sl[64+cb+1]) + xx.y);
    o.z = frelu(fmaf(y.z, sl[cb+2], sl[64+cb+2]) + xx.z);
    o.w = frelu(fmaf(y.w, sl[cb+3], sl[64+cb+3]) + xx.w);
    ((float4*)out)[idx] = o;
  }
}

// ---------------------------------------------------------------------------
extern "C" void kernel_launch(void* const* d_in, const int* in_sizes, int n_in,
                              void* d_out, int out_size, void* d_ws, size_t ws_size,
                              hipStream_t stream)
{
  (void)n_in; (void)out_size; (void)ws_size;
  const float* p   = (const float*)d_in[0];
  const float* x   = (const float*)d_in[1];
  const int*   knn = (const int*)  d_in[2];
  const float* W1  = (const float*)d_in[3];
  const float* Wv  = (const float*)d_in[4];
  const float* Wp1 = (const float*)d_in[5];
  const float* Wp2 = (const float*)d_in[6];
  const float* Ww  = (const float*)d_in[7];
  const float* W3  = (const float*)d_in[8];
  const float* g1  = (const float*)d_in[9];
  const float* b1  = (const float*)d_in[10];
  const float* g2  = (const float*)d_in[11];
  const float* b2  = (const float*)d_in[12];
  const float* g3  = (const float*)d_in[13];
  const float* b3  = (const float*)d_in[14];
  const int N = in_sizes[0] / 3;
  const float invN = 1.f / (float)N;

  float* ws = (float*)d_ws;
  float* y        = ws;                        // N*64  (y1, then y3)
  float* v        = y + (size_t)N*64;          // N*64
  float* mixed    = v + (size_t)N*64;          // N*64
  float* hw       = mixed + (size_t)N*64;      // N*8
  float* wp2wT    = hw + (size_t)N*8;          // 512
  float* partials = wp2wT + 512;               // GRID_MIX*128
  float* ss1      = partials + (size_t)GRID_MIX*128;
  float* ss2      = ss1 + 128;
  float* ss3      = ss2 + 128;

  wp2w_k<<<1, 64, 0, stream>>>(Wp2, Ww, wp2wT);
  gemm64_k<0><<<GRID_GEMM, 256, 0, stream>>>(x, W1, nullptr, nullptr, y, nullptr, partials, N);
  finalize_k<<<1, 256, 0, stream>>>(partials, GRID_GEMM, g1, b1, ss1, invN);
  gemm64_k<1><<<GRID_GEMM, 256, 0, stream>>>(y, Wv, Ww, ss1, v, hw, nullptr, N);
  mixer_k<<<GRID_MIX, 256, 0, stream>>>(p, knn, v, hw, Wp1, Wp2, wp2wT, mixed, partials, N);
  finalize_k<<<1, 256, 0, stream>>>(partials, GRID_MIX, g2, b2, ss2, invN);
  gemm64_k<2><<<GRID_GEMM, 256, 0, stream>>>(mixed, W3, nullptr, ss2, y, nullptr, partials, N);
  finalize_k<<<1, 256, 0, stream>>>(partials, GRID_GEMM, g3, b3, ss3, invN);
  final_k<<<GRID_ELT, 256, 0, stream>>>(y, x, ss3, (float*)d_out, N*16);
}

// Round 3
// 413.773 us; speedup vs baseline: 1.6967x; 1.6967x over previous
//
#include <hip/hip_runtime.h>
#include <hip/hip_fp16.h>

#define EPSV 1e-5f
#define PST 2048
#define GRID_GEMM 1024
#define GRID_MIX  1024
#define GRID_ELT  1024

typedef _Float16 h2_t __attribute__((ext_vector_type(2)));   // arithmetic
typedef __fp16  fp16x2 __attribute__((ext_vector_type(2)));  // builtin interop

__device__ __forceinline__ float frelu(float x) { return fmaxf(x, 0.f); }

__device__ __forceinline__ float rdl(float v, int l) {
  return __int_as_float(__builtin_amdgcn_readlane(__float_as_int(v), l));
}
__device__ __forceinline__ unsigned int pkrtz(float lo, float hi) {
  fp16x2 h = __builtin_amdgcn_cvt_pkrtz(lo, hi);
  return __builtin_bit_cast(unsigned int, h);
}
__device__ __forceinline__ float fdot2u(unsigned int a, unsigned int b, float c) {
#if __has_builtin(__builtin_amdgcn_fdot2)
  return __builtin_amdgcn_fdot2(__builtin_bit_cast(fp16x2, a),
                                __builtin_bit_cast(fp16x2, b), c, false);
#else
  h2_t ah = __builtin_bit_cast(h2_t, a), bh = __builtin_bit_cast(h2_t, b);
  return c + (float)ah[0]*(float)bh[0] + (float)ah[1]*(float)bh[1];
#endif
}

// ---------------------------------------------------------------------------
// wp2wT[g][a] = sum_c Wp2[a][c] * Ww[c][g]   (8 x 64, fp32)
__global__ __launch_bounds__(256) void wp2w_k(const float* __restrict__ Wp2,
                                             const float* __restrict__ Ww,
                                             float* __restrict__ wp2wT)
{
  const int t = threadIdx.x, a = t >> 2, qq = t & 3;
  float acc[8] = {0,0,0,0,0,0,0,0};
#pragma unroll
  for (int cc = 0; cc < 16; ++cc) {
    const int c = qq*16 + cc;
    const float wv = Wp2[a*64 + c];
#pragma unroll
    for (int g = 0; g < 8; ++g) acc[g] = fmaf(wv, Ww[c*8 + g], acc[g]);
  }
#pragma unroll
  for (int g = 0; g < 8; ++g) {
    acc[g] += __shfl_xor(acc[g], 1);
    acc[g] += __shfl_xor(acc[g], 2);
  }
  if (qq == 0) {
#pragma unroll
    for (int g = 0; g < 8; ++g) wp2wT[g*64 + a] = acc[g];
  }
}

// ---------------------------------------------------------------------------
// Readlane GEMM: out[N,64] = preop(in) @ W.  W in 64 VGPRs (lane = out chan),
// x tile in 16 VGPRs (lane = in chan), v_readlane broadcasts scalars.
// MODE0: no preop, stats partials. MODE1: preop(ss), + outw = preop(in)@Ww.
// MODE2: preop(ss), stats partials.
template<int MODE>
__global__ __launch_bounds__(256, 4) void gemm_rl_k(
    const float* __restrict__ in, const float* __restrict__ W,
    const float* __restrict__ Ww, const float* __restrict__ ss,
    float* __restrict__ out, float* __restrict__ outw,
    float* __restrict__ partials, int N)
{
  __shared__ float lds[(MODE == 1) ? (512 + 4*1088 + 512) : 512];
  const int t = threadIdx.x, lane = t & 63, w = t >> 6;
  float* const red = lds;                              // [512]
  float* const xw  = lds + 512 + w*1088;               // MODE1: [64 d][17]
  float* const Wwl = lds + 512 + 4*1088;               // MODE1: [512]

  float wreg[64];
#pragma unroll
  for (int d = 0; d < 64; ++d) wreg[d] = W[d*64 + lane];
  float sc = 1.f, sh = 0.f;
  if (MODE != 0) { sc = ss[lane]; sh = ss[64 + lane]; }
  if (MODE == 1) {
    for (int i = t; i < 512; i += 256) Wwl[i] = Ww[i];
    __syncthreads();
  }

  float ssum = 0.f, sq = 0.f;
  const int ntiles = (N + 15) >> 4;
  const int nwaves = gridDim.x * 4;
  for (int tile = blockIdx.x*4 + w; tile < ntiles; tile += nwaves) {
    const int r0 = tile << 4;
    float xv[16];
    if (r0 + 16 <= N) {
#pragma unroll
      for (int rr = 0; rr < 16; ++rr) xv[rr] = in[(size_t)(r0+rr)*64 + lane];
    } else {
#pragma unroll
      for (int rr = 0; rr < 16; ++rr)
        xv[rr] = (r0+rr < N) ? in[(size_t)(r0+rr)*64 + lane] : 0.f;
    }
    if (MODE != 0) {
#pragma unroll
      for (int rr = 0; rr < 16; ++rr) xv[rr] = frelu(fmaf(xv[rr], sc, sh));
    }
    if (MODE == 1) {
#pragma unroll
      for (int rr = 0; rr < 16; ++rr) xw[lane*17 + rr] = xv[rr];
    }
    float acc[16];
#pragma unroll
    for (int rr = 0; rr < 16; ++rr) acc[rr] = 0.f;
#pragma unroll
    for (int d = 0; d < 64; ++d) {
#pragma unroll
      for (int rr = 0; rr < 16; ++rr)
        acc[rr] = fmaf(rdl(xv[rr], d), wreg[d], acc[rr]);
    }
    const int rlim = min(16, N - r0);
#pragma unroll
    for (int rr = 0; rr < 16; ++rr) {
      if (rr < rlim) {
        out[(size_t)(r0+rr)*64 + lane] = acc[rr];
        if (MODE != 1) { ssum += acc[rr]; sq = fmaf(acc[rr], acc[rr], sq); }
      }
    }
    if (MODE == 1) {
      const int g = lane & 7, rb = lane >> 3;
#pragma unroll
      for (int half = 0; half < 2; ++half) {
        const int r = half*8 + rb;
        float a2 = 0.f;
#pragma unroll
        for (int d = 0; d < 64; ++d) a2 = fmaf(xw[d*17 + r], Wwl[d*8 + g], a2);
        if (r < rlim) outw[(size_t)(r0+r)*8 + g] = a2;
      }
    }
  }
  if (MODE != 1) {
    __syncthreads();
    red[w*128 + lane] = ssum; red[w*128 + 64 + lane] = sq;
    __syncthreads();
    if (t < 64) {
      const float s = red[t] + red[128+t] + red[256+t] + red[384+t];
      const float q = red[64+t] + red[192+t] + red[320+t] + red[448+t];
      partials[(size_t)t*PST + blockIdx.x]      = s;
      partials[(size_t)(64+t)*PST + blockIdx.x] = q;
    }
  }
}

// ---------------------------------------------------------------------------
// 64-block finalize: block c reads its two coalesced partial rows.
__global__ __launch_bounds__(256) void fin_k(const float* __restrict__ partials,
    int nblk, const float* __restrict__ gamma, const float* __restrict__ beta,
    float* __restrict__ ss, float invN)
{
  __shared__ float red[8];
  const int c = blockIdx.x;
  float s = 0.f, q = 0.f;
  for (int i = threadIdx.x; i < nblk; i += 256) {
    s += partials[(size_t)c*PST + i];
    q += partials[(size_t)(64+c)*PST + i];
  }
#pragma unroll
  for (int mk = 1; mk < 64; mk <<= 1) {
    s += __shfl_xor(s, mk);
    q += __shfl_xor(q, mk);
  }
  const int w = threadIdx.x >> 6;
  if ((threadIdx.x & 63) == 0) { red[w*2] = s; red[w*2+1] = q; }
  __syncthreads();
  if (threadIdx.x == 0) {
    const float S = red[0]+red[2]+red[4]+red[6];
    const float Q = red[1]+red[3]+red[5]+red[7];
    const float mean = S*invN;
    const float var  = Q*invN - mean*mean;
    const float scale = gamma[c] * rsqrtf(var + EPSV);
    ss[c] = scale; ss[64+c] = beta[c] - mean*scale;
  }
}

// ---------------------------------------------------------------------------
// Wave-per-point mixer, f16 e-path. LDS 28.5KB/block -> 4 blocks/CU.
__global__ __launch_bounds__(256, 4) void mixer_k(
    const float* __restrict__ p, const int* __restrict__ knn,
    const float* __restrict__ v, const float* __restrict__ hw,
    const float* __restrict__ Wp1, const float* __restrict__ Wp2,
    const float* __restrict__ wp2wT, float* __restrict__ mixed,
    float* __restrict__ partials, int N)
{
  __shared__ unsigned int lds[7136];
  unsigned int* const Wp2h = lds;            // [64 c][36] f16 pairs over d
  unsigned int* const wwh  = lds + 2304;     // [8 g][36] f16 pairs over d
  const int t = threadIdx.x, lane = t & 63, w = t >> 6;
  unsigned int* const wb   = lds + 2592 + w*1008;
  unsigned int* const e_h  = wb;             // [16 k][36] f16 pairs over d
  unsigned int* const wh_s = wb + 576;       // [16 k][4]  f16 pairs over g
  unsigned int* const S_h  = wb + 640;       // [8 g][36]  f16 pairs over d
  int*          const j_s  = (int*)(wb + 928);   // [16]
  float*        const pd   = (float*)(wb + 944); // [16][4]
  float*        const red  = (float*)(lds + 6624); // [512]

  for (int idx = t; idx < 2048; idx += 256) {
    const int m = idx >> 6, c = idx & 63;
    Wp2h[c*36 + m] = pkrtz(Wp2[(2*m)*64 + c], Wp2[(2*m+1)*64 + c]);
  }
  {
    const int g = t >> 5, m = t & 31;
    if (t < 256) wwh[g*36 + m] = pkrtz(wp2wT[g*64 + 2*m], wp2wT[g*64 + 2*m+1]);
  }
  __syncthreads();

  const float w1x = Wp1[lane], w1y = Wp1[64+lane], w1z = Wp1[128+lane];
  const int kb = lane >> 2, gg = lane & 3;
  const int g8 = lane >> 3;
  const unsigned int wsh = (unsigned)(g8 & 1) * 16u;
  const int wcol = g8 >> 1;
  const bool evenl = ((lane & 1) == 0);
  float ssum = 0.f, sq = 0.f;
  const int nwaves = gridDim.x * 4;

  for (int i = blockIdx.x*4 + w; i < N; i += nwaves) {
    int jreg = 0;
    if (lane < 16) {
      jreg = knn[(size_t)i*16 + lane];
      j_s[lane] = jreg;
      const float pix = p[(size_t)i*3], piy = p[(size_t)i*3+1], piz = p[(size_t)i*3+2];
      float4 d4;
      d4.x = p[(size_t)jreg*3]   - pix;
      d4.y = p[(size_t)jreg*3+1] - piy;
      d4.z = p[(size_t)jreg*3+2] - piz;
      d4.w = 0.f;
      *(float4*)(pd + lane*4) = d4;
    }
    // ---- Phase A: e'[k] per lane=d; pack f16 d-pairs into e_h
    float ep[16];
#pragma unroll
    for (int k = 0; k < 16; ++k) {
      const float4 d4 = *(const float4*)(pd + k*4);
      ep[k] = frelu(fmaf(d4.x, w1x, fmaf(d4.y, w1y, d4.z*w1z)));
    }
#pragma unroll
    for (int k = 0; k < 16; k += 2) {
      const float n0 = __shfl_xor(ep[k], 1);
      const float n1 = __shfl_xor(ep[k+1], 1);
      const float lo = evenl ? ep[k] : n1;
      const float hi = evenl ? n0 : ep[k+1];
      const int row = k + (evenl ? 0 : 1);
      e_h[row*36 + (lane>>1)] = pkrtz(lo, hi);
    }
    // ---- Phase B: energies for (kb, g=2gg,2gg+1) via fdot2
    const int jb = j_s[kb];
    const float2 hw2 = *(const float2*)(hw + (size_t)jb*8 + 2*gg);
    float en0 = hw2.x, en1 = hw2.y;
    const unsigned int* erow = e_h + kb*36;
    const unsigned int* wr0  = wwh + (2*gg)*36;
    const unsigned int* wr1  = wwh + (2*gg+1)*36;
#pragma unroll
    for (int m4 = 0; m4 < 8; ++m4) {
      const uint4 e4 = *(const uint4*)(erow + m4*4);
      const uint4 a0 = *(const uint4*)(wr0 + m4*4);
      const uint4 a1 = *(const uint4*)(wr1 + m4*4);
      en0 = fdot2u(e4.x, a0.x, en0); en1 = fdot2u(e4.x, a1.x, en1);
      en0 = fdot2u(e4.y, a0.y, en0); en1 = fdot2u(e4.y, a1.y, en1);
      en0 = fdot2u(e4.z, a0.z, en0); en1 = fdot2u(e4.z, a1.z, en1);
      en0 = fdot2u(e4.w, a0.w, en0); en1 = fdot2u(e4.w, a1.w, en1);
    }
    // softmax over k (lanes stride 4)
    float m0 = en0, m1 = en1;
#pragma unroll
    for (int mk = 4; mk < 64; mk <<= 1) {
      m0 = fmaxf(m0, __shfl_xor(m0, mk));
      m1 = fmaxf(m1, __shfl_xor(m1, mk));
    }
    const float p0 = __expf(en0 - m0), p1 = __expf(en1 - m1);
    float s0 = p0, s1 = p1;
#pragma unroll
    for (int mk = 4; mk < 64; mk <<= 1) {
      s0 += __shfl_xor(s0, mk);
      s1 += __shfl_xor(s1, mk);
    }
    wh_s[kb*4 + gg] = pkrtz(p0/s0, p1/s1);
    // ---- Phase S: S[g][d=lane] = sum_k w[k][g] * e'[k][d]  (pk_fma_f16)
    h2_t S2[4];
#pragma unroll
    for (int j2 = 0; j2 < 4; ++j2) S2[j2] = h2_t{(_Float16)0.f, (_Float16)0.f};
#pragma unroll
    for (int k = 0; k < 16; ++k) {
      const uint4 wk = *(const uint4*)(wh_s + k*4);
      const h2_t e2 = __builtin_bit_cast(h2_t, pkrtz(ep[k], ep[k]));
      S2[0] = __builtin_bit_cast(h2_t, wk.x) * e2 + S2[0];
      S2[1] = __builtin_bit_cast(h2_t, wk.y) * e2 + S2[1];
      S2[2] = __builtin_bit_cast(h2_t, wk.z) * e2 + S2[2];
      S2[3] = __builtin_bit_cast(h2_t, wk.w) * e2 + S2[3];
    }
#pragma unroll
    for (int j2 = 0; j2 < 4; ++j2) {
      const unsigned int own = __builtin_bit_cast(unsigned int, S2[j2]);
      const unsigned int nb = (unsigned int)__shfl_xor((int)own, 1);
      const unsigned int u = evenl ? ((own & 0xffffu) | (nb << 16))
                                   : ((nb >> 16) | (own & 0xffff0000u));
      const int row = 2*j2 + (evenl ? 0 : 1);
      S_h[row*36 + (lane>>1)] = u;
    }
    // ---- vsum: coalesced random v-row gathers, w from f16 LDS
    float acc = 0.f;
#pragma unroll
    for (int k = 0; k < 16; ++k) {
      const int jk = __builtin_amdgcn_readlane(jreg, k);
      const float vv = v[(size_t)jk*64 + lane];
      const unsigned int wk = wh_s[k*4 + wcol];
      const h2_t wh = __builtin_bit_cast(h2_t, wk >> wsh);
      acc = fmaf((float)wh[0], vv, acc);
    }
    // ---- e-part: acc += sum_d S[g8][d] * Wp2[d][c=lane]
    const unsigned int* srow = S_h + g8*36;
    const unsigned int* prow = Wp2h + lane*36;
#pragma unroll
    for (int m4 = 0; m4 < 8; ++m4) {
      const uint4 s4 = *(const uint4*)(srow + m4*4);
      const uint4 wp = *(const uint4*)(prow + m4*4);
      acc = fdot2u(s4.x, wp.x, acc);
      acc = fdot2u(s4.y, wp.y, acc);
      acc = fdot2u(s4.z, wp.z, acc);
      acc = fdot2u(s4.w, wp.w, acc);
    }
    mixed[(size_t)i*64 + lane] = acc;
    ssum += acc; sq = fmaf(acc, acc, sq);
  }
  __syncthreads();
  red[w*128 + lane] = ssum; red[w*128 + 64 + lane] = sq;
  __syncthreads();
  if (t < 64) {
    const float s = red[t] + red[128+t] + red[256+t] + red[384+t];
    const float q = red[64+t] + red[192+t] + red[320+t] + red[448+t];
    partials[(size_t)t*PST + blockIdx.x]      = s;
    partials[(size_t)(64+t)*PST + blockIdx.x] = q;
  }
}

// ---------------------------------------------------------------------------
__global__ __launch_bounds__(256) void final_k(const float* __restrict__ y3,
    const float* __restrict__ x, const float* __restrict__ ss,
    float* __restrict__ out, int n4)
{
  __shared__ float sl[128];
  if (threadIdx.x < 128) sl[threadIdx.x] = ss[threadIdx.x];
  __syncthreads();
  for (int idx = blockIdx.x*256 + threadIdx.x; idx < n4; idx += gridDim.x*256) {
    const int cb = (idx & 15) << 2;
    const float4 y  = ((const float4*)y3)[idx];
    const float4 xx = ((const float4*)x)[idx];
    float4 o;
    o.x = frelu(fmaf(y.x, sl[cb],   sl[64+cb])   + xx.x);
    o.y = frelu(fmaf(y.y, sl[cb+1], sl[64+cb+1]) + xx.y);
    o.z = frelu(fmaf(y.z, sl[cb+2], sl[64+cb+2]) + xx.z);
    o.w = frelu(fmaf(y.w, sl[cb+3], sl[64+cb+3]) + xx.w);
    ((float4*)out)[idx] = o;
  }
}

// ---------------------------------------------------------------------------
extern "C" void kernel_launch(void* const* d_in, const int* in_sizes, int n_in,
                              void* d_out, int out_size, void* d_ws, size_t ws_size,
                              hipStream_t stream)
{
  (void)n_in; (void)out_size; (void)ws_size;
  const float* p   = (const float*)d_in[0];
  const float* x   = (const float*)d_in[1];
  const int*   knn = (const int*)  d_in[2];
  const float* W1  = (const float*)d_in[3];
  const float* Wv  = (const float*)d_in[4];
  const float* Wp1 = (const float*)d_in[5];
  const float* Wp2 = (const float*)d_in[6];
  const float* Ww  = (const float*)d_in[7];
  const float* W3  = (const float*)d_in[8];
  const float* g1  = (const float*)d_in[9];
  const float* b1  = (const float*)d_in[10];
  const float* g2  = (const float*)d_in[11];
  const float* b2  = (const float*)d_in[12];
  const float* g3  = (const float*)d_in[13];
  const float* b3  = (const float*)d_in[14];
  const int N = in_sizes[0] / 3;
  const float invN = 1.f / (float)N;

  float* ws = (float*)d_ws;
  float* y        = ws;                        // N*64 (y1, then y3)
  float* v        = y + (size_t)N*64;          // N*64
  float* mixed    = v + (size_t)N*64;          // N*64
  float* hw       = mixed + (size_t)N*64;      // N*8
  float* wp2wT    = hw + (size_t)N*8;          // 512
  float* partials = wp2wT + 512;               // 128*PST
  float* ss1      = partials + (size_t)128*PST;
  float* ss2      = ss1 + 128;
  float* ss3      = ss2 + 128;

  wp2w_k<<<1, 256, 0, stream>>>(Wp2, Ww, wp2wT);
  gemm_rl_k<0><<<GRID_GEMM, 256, 0, stream>>>(x, W1, nullptr, nullptr, y, nullptr, partials, N);
  fin_k<<<64, 256, 0, stream>>>(partials, GRID_GEMM, g1, b1, ss1, invN);
  gemm_rl_k<1><<<GRID_GEMM, 256, 0, stream>>>(y, Wv, Ww, ss1, v, hw, nullptr, N);
  mixer_k<<<GRID_MIX, 256, 0, stream>>>(p, knn, v, hw, Wp1, Wp2, wp2wT, mixed, partials, N);
  fin_k<<<64, 256, 0, stream>>>(partials, GRID_MIX, g2, b2, ss2, invN);
  gemm_rl_k<2><<<GRID_GEMM, 256, 0, stream>>>(mixed, W3, nullptr, ss2, y, nullptr, partials, N);
  fin_k<<<64, 256, 0, stream>>>(partials, GRID_GEMM, g3, b3, ss3, invN);
  final_k<<<GRID_ELT, 256, 0, stream>>>(y, x, ss3, (float*)d_out, N*16);
}

// Round 4
// 216.584 us; speedup vs baseline: 3.2415x; 1.9105x over previous
//
#include <hip/hip_runtime.h>
#include <hip/hip_fp16.h>

#define EPSV 1e-5f
#define PST 2048
#define GRID_GEMM 782
#define GRID_MIX  1280
#define GRID_ELT  1024

typedef _Float16 h2_t __attribute__((ext_vector_type(2)));   // arithmetic
typedef __fp16  fp16x2 __attribute__((ext_vector_type(2)));  // builtin interop
typedef _Float16 f16x8 __attribute__((ext_vector_type(8)));  // MFMA A/B frag
typedef float    f32x4 __attribute__((ext_vector_type(4)));  // MFMA C/D frag

__device__ __forceinline__ float frelu(float x) { return fmaxf(x, 0.f); }

__device__ __forceinline__ float rdl(float v, int l) {
  return __int_as_float(__builtin_amdgcn_readlane(__float_as_int(v), l));
}
__device__ __forceinline__ unsigned int pkrtz(float lo, float hi) {
  fp16x2 h = __builtin_amdgcn_cvt_pkrtz(lo, hi);
  return __builtin_bit_cast(unsigned int, h);
}
__device__ __forceinline__ float fdot2u(unsigned int a, unsigned int b, float c) {
#if __has_builtin(__builtin_amdgcn_fdot2)
  return __builtin_amdgcn_fdot2(__builtin_bit_cast(fp16x2, a),
                                __builtin_bit_cast(fp16x2, b), c, false);
#else
  h2_t ah = __builtin_bit_cast(h2_t, a), bh = __builtin_bit_cast(h2_t, b);
  return c + (float)ah[0]*(float)bh[0] + (float)ah[1]*(float)bh[1];
#endif
}
__device__ __forceinline__ f16x8 mk8(unsigned a, unsigned b, unsigned c, unsigned d) {
  uint4 u; u.x = a; u.y = b; u.z = c; u.w = d;
  return __builtin_bit_cast(f16x8, u);
}
__device__ __forceinline__ f32x4 mfma16(f16x8 a, f16x8 b, f32x4 c) {
  return __builtin_amdgcn_mfma_f32_16x16x32_f16(a, b, c, 0, 0, 0);
}

// ---------------------------------------------------------------------------
// wp2wT[g][a] = sum_c Wp2[a][c] * Ww[c][g]   (8 x 64, fp32)
__global__ __launch_bounds__(256) void wp2w_k(const float* __restrict__ Wp2,
                                             const float* __restrict__ Ww,
                                             float* __restrict__ wp2wT)
{
  const int t = threadIdx.x, a = t >> 2, qq = t & 3;
  float acc[8] = {0,0,0,0,0,0,0,0};
#pragma unroll
  for (int cc = 0; cc < 16; ++cc) {
    const int c = qq*16 + cc;
    const float wv = Wp2[a*64 + c];
#pragma unroll
    for (int g = 0; g < 8; ++g) acc[g] = fmaf(wv, Ww[c*8 + g], acc[g]);
  }
#pragma unroll
  for (int g = 0; g < 8; ++g) {
    acc[g] += __shfl_xor(acc[g], 1);
    acc[g] += __shfl_xor(acc[g], 2);
  }
  if (qq == 0) {
#pragma unroll
    for (int g = 0; g < 8; ++g) wp2wT[g*64 + a] = acc[g];
  }
}

// ---------------------------------------------------------------------------
// MFMA f16 GEMM: out[N,64] = preop(in) @ W.
// A-frag: row = lane&15, k = 8*(lane>>4)+m.  B-frag: col = lane&15, same k.
// C/D: col = lane&15, row = 4*(lane>>4)+j  (m89-verified layout).
// MODE0: no preop, stats partials. MODE1: preop(ss), + outw = preop(in)@Ww.
// MODE2: preop(ss), stats partials.
template<int MODE>
__global__ __launch_bounds__(256, 4) void gemm_mfma_k(
    const float* __restrict__ in, const float* __restrict__ W,
    const float* __restrict__ Ww, const float* __restrict__ ss,
    float* __restrict__ out, float* __restrict__ outw,
    float* __restrict__ partials, int N)
{
  __shared__ float red[512];
  __shared__ unsigned short xh[4][16*72];   // per-wave f16 tile [16 r][72 pad]
  const int t = threadIdx.x, lane = t & 63, w = t >> 6;
  const int r16 = lane & 15, q = lane >> 4;
  unsigned short* const xw = &xh[w][0];

  // --- W fragments (held in VGPRs for the whole kernel) ---
  f16x8 bw[2][4];
#pragma unroll
  for (int kb = 0; kb < 2; ++kb) {
#pragma unroll
    for (int tt = 0; tt < 4; ++tt) {
      const int kbase = 32*kb + 8*q;
      const int cc = 16*tt + r16;
      unsigned u0 = pkrtz(W[(kbase+0)*64 + cc], W[(kbase+1)*64 + cc]);
      unsigned u1 = pkrtz(W[(kbase+2)*64 + cc], W[(kbase+3)*64 + cc]);
      unsigned u2 = pkrtz(W[(kbase+4)*64 + cc], W[(kbase+5)*64 + cc]);
      unsigned u3 = pkrtz(W[(kbase+6)*64 + cc], W[(kbase+7)*64 + cc]);
      bw[kb][tt] = mk8(u0, u1, u2, u3);
    }
  }
  f16x8 bg[2];
  if (MODE == 1) {
#pragma unroll
    for (int kb = 0; kb < 2; ++kb) {
      const int kbase = 32*kb + 8*q;
      unsigned u[4];
#pragma unroll
      for (int mm = 0; mm < 4; ++mm) {
        float g0 = (r16 < 8) ? Ww[(kbase + 2*mm    )*8 + r16] : 0.f;
        float g1 = (r16 < 8) ? Ww[(kbase + 2*mm + 1)*8 + r16] : 0.f;
        u[mm] = pkrtz(g0, g1);
      }
      bg[kb] = mk8(u[0], u[1], u[2], u[3]);
    }
  }
  float sc4[4], sh4[4];
  if (MODE != 0) {
#pragma unroll
    for (int j = 0; j < 4; ++j) {
      sc4[j] = ss[4*r16 + j];
      sh4[j] = ss[64 + 4*r16 + j];
    }
  }

  float S4[4] = {0,0,0,0}, Q4[4] = {0,0,0,0};
  const int ntiles = (N + 15) >> 4;
  for (int tile = blockIdx.x*4 + w; tile < ntiles; tile += GRID_GEMM*4) {
    const int r0 = tile << 4;
    const bool full = (r0 + 16 <= N);
    // --- stage 16x64 f32 -> f16 LDS tile (BN+relu fused) ---
#pragma unroll
    for (int i = 0; i < 4; ++i) {
      const int row = q + 4*i;
      float4 xv = {0.f, 0.f, 0.f, 0.f};
      const bool rok = full || (r0 + row < N);
      if (rok) xv = *(const float4*)(in + (size_t)(r0 + row)*64 + 4*r16);
      if (MODE != 0) {
        xv.x = frelu(fmaf(xv.x, sc4[0], sh4[0]));
        xv.y = frelu(fmaf(xv.y, sc4[1], sh4[1]));
        xv.z = frelu(fmaf(xv.z, sc4[2], sh4[2]));
        xv.w = frelu(fmaf(xv.w, sc4[3], sh4[3]));
        if (!rok) { xv.x = 0.f; xv.y = 0.f; xv.z = 0.f; xv.w = 0.f; }
      }
      uint2 u2v; u2v.x = pkrtz(xv.x, xv.y); u2v.y = pkrtz(xv.z, xv.w);
      *(uint2*)(xw + row*72 + 4*r16) = u2v;
    }
    // --- A fragments (same-wave LDS dependency; compiler inserts waits) ---
    const f16x8 a0 = __builtin_bit_cast(f16x8, *(const uint4*)(xw + r16*72 + 8*q));
    const f16x8 a1 = __builtin_bit_cast(f16x8, *(const uint4*)(xw + r16*72 + 8*q + 32));
    // --- MFMA ---
    f32x4 acc[4];
#pragma unroll
    for (int tt = 0; tt < 4; ++tt) {
      f32x4 z = {0.f, 0.f, 0.f, 0.f};
      z = mfma16(a0, bw[0][tt], z);
      acc[tt] = mfma16(a1, bw[1][tt], z);
    }
    // --- store + stats ---
#pragma unroll
    for (int tt = 0; tt < 4; ++tt) {
#pragma unroll
      for (int j = 0; j < 4; ++j) {
        if (full || (r0 + 4*q + j < N))
          out[(size_t)(r0 + 4*q + j)*64 + 16*tt + r16] = acc[tt][j];
      }
      if (MODE != 1) {
        S4[tt] += acc[tt][0] + acc[tt][1] + acc[tt][2] + acc[tt][3];
        Q4[tt] = fmaf(acc[tt][0], acc[tt][0], Q4[tt]);
        Q4[tt] = fmaf(acc[tt][1], acc[tt][1], Q4[tt]);
        Q4[tt] = fmaf(acc[tt][2], acc[tt][2], Q4[tt]);
        Q4[tt] = fmaf(acc[tt][3], acc[tt][3], Q4[tt]);
      }
    }
    if (MODE == 1) {
      f32x4 accw = {0.f, 0.f, 0.f, 0.f};
      accw = mfma16(a0, bg[0], accw);
      accw = mfma16(a1, bg[1], accw);
      if (r16 < 8) {
#pragma unroll
        for (int j = 0; j < 4; ++j) {
          if (full || (r0 + 4*q + j < N))
            outw[(size_t)(r0 + 4*q + j)*8 + r16] = accw[j];
        }
      }
    }
  }
  if (MODE != 1) {
    // reduce over row-groups (lane bits 4,5), then block-reduce
#pragma unroll
    for (int tt = 0; tt < 4; ++tt) {
      S4[tt] += __shfl_xor(S4[tt], 16); S4[tt] += __shfl_xor(S4[tt], 32);
      Q4[tt] += __shfl_xor(Q4[tt], 16); Q4[tt] += __shfl_xor(Q4[tt], 32);
    }
    if (lane < 16) {
#pragma unroll
      for (int tt = 0; tt < 4; ++tt) {
        red[w*128 + tt*16 + lane]      = S4[tt];
        red[w*128 + 64 + tt*16 + lane] = Q4[tt];
      }
    }
    __syncthreads();
    if (t < 64) {
      const float s = red[t] + red[128+t] + red[256+t] + red[384+t];
      const float qq = red[64+t] + red[192+t] + red[320+t] + red[448+t];
      partials[(size_t)t*PST + blockIdx.x]      = s;
      partials[(size_t)(64+t)*PST + blockIdx.x] = qq;
    }
  }
}

// ---------------------------------------------------------------------------
// 64-block finalize: block c reads its two coalesced partial rows.
__global__ __launch_bounds__(256) void fin_k(const float* __restrict__ partials,
    int nblk, const float* __restrict__ gamma, const float* __restrict__ beta,
    float* __restrict__ ss, float invN)
{
  __shared__ float red[8];
  const int c = blockIdx.x;
  float s = 0.f, q = 0.f;
  for (int i = threadIdx.x; i < nblk; i += 256) {
    s += partials[(size_t)c*PST + i];
    q += partials[(size_t)(64+c)*PST + i];
  }
#pragma unroll
  for (int mk = 1; mk < 64; mk <<= 1) {
    s += __shfl_xor(s, mk);
    q += __shfl_xor(q, mk);
  }
  const int w = threadIdx.x >> 6;
  if ((threadIdx.x & 63) == 0) { red[w*2] = s; red[w*2+1] = q; }
  __syncthreads();
  if (threadIdx.x == 0) {
    const float S = red[0]+red[2]+red[4]+red[6];
    const float Q = red[1]+red[3]+red[5]+red[7];
    const float mean = S*invN;
    const float var  = Q*invN - mean*mean;
    const float scale = gamma[c] * rsqrtf(var + EPSV);
    ss[c] = scale; ss[64+c] = beta[c] - mean*scale;
  }
}

// ---------------------------------------------------------------------------
// Wave-per-point mixer, f16 e-path. LDS 27.8KB/block -> 5 blocks/CU.
__global__ __launch_bounds__(256, 4) void mixer_k(
    const float* __restrict__ p, const int* __restrict__ knn,
    const float* __restrict__ v, const float* __restrict__ hw,
    const float* __restrict__ Wp1, const float* __restrict__ Wp2,
    const float* __restrict__ wp2wT, float* __restrict__ mixed,
    float* __restrict__ partials, int N)
{
  __shared__ unsigned int lds[6944];
  unsigned int* const Wp2h = lds;            // [64 c][36] f16 pairs over d
  unsigned int* const wwh  = lds + 2304;     // [8 g][36] f16 pairs over d
  const int t = threadIdx.x, lane = t & 63, w = t >> 6;
  unsigned int* const wb   = lds + 2592 + w*960;
  unsigned int* const e_h  = wb;             // [16 k][36] f16 pairs over d
  unsigned int* const wh_s = wb + 576;       // [16 k][4]  f16 pairs over g
  unsigned int* const S_h  = wb + 640;       // [8 g][36]  f16 pairs over d
  int*          const j_s  = (int*)(wb + 928);   // [16]
  float*        const red  = (float*)(lds + 2592 + 4*960); // [512]

  for (int idx = t; idx < 2048; idx += 256) {
    const int m = idx >> 6, c = idx & 63;
    Wp2h[c*36 + m] = pkrtz(Wp2[(2*m)*64 + c], Wp2[(2*m+1)*64 + c]);
  }
  {
    const int g = t >> 5, m = t & 31;
    if (t < 256) wwh[g*36 + m] = pkrtz(wp2wT[g*64 + 2*m], wp2wT[g*64 + 2*m+1]);
  }
  __syncthreads();

  const float w1x = Wp1[lane], w1y = Wp1[64+lane], w1z = Wp1[128+lane];
  const int kb = lane >> 2, gg = lane & 3;
  const int g8 = lane >> 3;
  const unsigned int wsh = (unsigned)(g8 & 1) * 16u;
  const int wcol = g8 >> 1;
  const bool evenl = ((lane & 1) == 0);
  float ssum = 0.f, sq = 0.f;
  const int nwaves = gridDim.x * 4;

  for (int i = blockIdx.x*4 + w; i < N; i += nwaves) {
    float dx = 0.f, dy = 0.f, dz = 0.f;
    int jreg = 0;
    if (lane < 16) {
      jreg = knn[(size_t)i*16 + lane];
      j_s[lane] = jreg;
      dx = p[(size_t)jreg*3]   - p[(size_t)i*3];
      dy = p[(size_t)jreg*3+1] - p[(size_t)i*3+1];
      dz = p[(size_t)jreg*3+2] - p[(size_t)i*3+2];
    }
    // ---- Phase A: e'[k] per lane=d (deltas broadcast via readlane)
    float ep[16];
#pragma unroll
    for (int k = 0; k < 16; ++k) {
      ep[k] = frelu(fmaf(rdl(dx,k), w1x, fmaf(rdl(dy,k), w1y, rdl(dz,k)*w1z)));
    }
#pragma unroll
    for (int k = 0; k < 16; k += 2) {
      const float n0 = __shfl_xor(ep[k], 1);
      const float n1 = __shfl_xor(ep[k+1], 1);
      const float lo = evenl ? ep[k] : n1;
      const float hi = evenl ? n0 : ep[k+1];
      const int row = k + (evenl ? 0 : 1);
      e_h[row*36 + (lane>>1)] = pkrtz(lo, hi);
    }
    // ---- Phase B: energies for (kb, g=2gg,2gg+1) via fdot2
    const int jb = j_s[kb];
    const float2 hw2 = *(const float2*)(hw + (size_t)jb*8 + 2*gg);
    float en0 = hw2.x, en1 = hw2.y;
    const unsigned int* erow = e_h + kb*36;
    const unsigned int* wr0  = wwh + (2*gg)*36;
    const unsigned int* wr1  = wwh + (2*gg+1)*36;
#pragma unroll
    for (int m4 = 0; m4 < 8; ++m4) {
      const uint4 e4 = *(const uint4*)(erow + m4*4);
      const uint4 a0 = *(const uint4*)(wr0 + m4*4);
      const uint4 a1 = *(const uint4*)(wr1 + m4*4);
      en0 = fdot2u(e4.x, a0.x, en0); en1 = fdot2u(e4.x, a1.x, en1);
      en0 = fdot2u(e4.y, a0.y, en0); en1 = fdot2u(e4.y, a1.y, en1);
      en0 = fdot2u(e4.z, a0.z, en0); en1 = fdot2u(e4.z, a1.z, en1);
      en0 = fdot2u(e4.w, a0.w, en0); en1 = fdot2u(e4.w, a1.w, en1);
    }
    // softmax over k (lanes stride 4)
    float m0 = en0, m1 = en1;
#pragma unroll
    for (int mk = 4; mk < 64; mk <<= 1) {
      m0 = fmaxf(m0, __shfl_xor(m0, mk));
      m1 = fmaxf(m1, __shfl_xor(m1, mk));
    }
    const float p0 = __expf(en0 - m0), p1 = __expf(en1 - m1);
    float s0 = p0, s1 = p1;
#pragma unroll
    for (int mk = 4; mk < 64; mk <<= 1) {
      s0 += __shfl_xor(s0, mk);
      s1 += __shfl_xor(s1, mk);
    }
    wh_s[kb*4 + gg] = pkrtz(p0/s0, p1/s1);
    // ---- Phase S: S[g][d=lane] = sum_k w[k][g] * e'[k][d]  (pk_fma_f16)
    h2_t S2[4];
#pragma unroll
    for (int j2 = 0; j2 < 4; ++j2) S2[j2] = h2_t{(_Float16)0.f, (_Float16)0.f};
#pragma unroll
    for (int k = 0; k < 16; ++k) {
      const uint4 wk = *(const uint4*)(wh_s + k*4);
      const h2_t e2 = __builtin_bit_cast(h2_t, pkrtz(ep[k], ep[k]));
      S2[0] = __builtin_bit_cast(h2_t, wk.x) * e2 + S2[0];
      S2[1] = __builtin_bit_cast(h2_t, wk.y) * e2 + S2[1];
      S2[2] = __builtin_bit_cast(h2_t, wk.z) * e2 + S2[2];
      S2[3] = __builtin_bit_cast(h2_t, wk.w) * e2 + S2[3];
    }
#pragma unroll
    for (int j2 = 0; j2 < 4; ++j2) {
      const unsigned int own = __builtin_bit_cast(unsigned int, S2[j2]);
      const unsigned int nb = (unsigned int)__shfl_xor((int)own, 1);
      const unsigned int u = evenl ? ((own & 0xffffu) | (nb << 16))
                                   : ((nb >> 16) | (own & 0xffff0000u));
      const int row = 2*j2 + (evenl ? 0 : 1);
      S_h[row*36 + (lane>>1)] = u;
    }
    // ---- vsum: coalesced random v-row gathers, w from f16 LDS
    float acc = 0.f;
#pragma unroll
    for (int k = 0; k < 16; ++k) {
      const int jk = __builtin_amdgcn_readlane(jreg, k);
      const float vv = v[(size_t)jk*64 + lane];
      const unsigned int wk = wh_s[k*4 + wcol];
      const h2_t wh = __builtin_bit_cast(h2_t, wk >> wsh);
      acc = fmaf((float)wh[0], vv, acc);
    }
    // ---- e-part: acc += sum_d S[g8][d] * Wp2[d][c=lane]
    const unsigned int* srow = S_h + g8*36;
    const unsigned int* prow = Wp2h + lane*36;
#pragma unroll
    for (int m4 = 0; m4 < 8; ++m4) {
      const uint4 s4 = *(const uint4*)(srow + m4*4);
      const uint4 wp = *(const uint4*)(prow + m4*4);
      acc = fdot2u(s4.x, wp.x, acc);
      acc = fdot2u(s4.y, wp.y, acc);
      acc = fdot2u(s4.z, wp.z, acc);
      acc = fdot2u(s4.w, wp.w, acc);
    }
    mixed[(size_t)i*64 + lane] = acc;
    ssum += acc; sq = fmaf(acc, acc, sq);
  }
  __syncthreads();
  red[w*128 + lane] = ssum; red[w*128 + 64 + lane] = sq;
  __syncthreads();
  if (t < 64) {
    const float s = red[t] + red[128+t] + red[256+t] + red[384+t];
    const float q = red[64+t] + red[192+t] + red[320+t] + red[448+t];
    partials[(size_t)t*PST + blockIdx.x]      = s;
    partials[(size_t)(64+t)*PST + blockIdx.x] = q;
  }
}

// ---------------------------------------------------------------------------
__global__ __launch_bounds__(256) void final_k(const float* __restrict__ y3,
    const float* __restrict__ x, const float* __restrict__ ss,
    float* __restrict__ out, int n4)
{
  __shared__ float sl[128];
  if (threadIdx.x < 128) sl[threadIdx.x] = ss[threadIdx.x];
  __syncthreads();
  for (int idx = blockIdx.x*256 + threadIdx.x; idx < n4; idx += gridDim.x*256) {
    const int cb = (idx & 15) << 2;
    const float4 y  = ((const float4*)y3)[idx];
    const float4 xx = ((const float4*)x)[idx];
    float4 o;
    o.x = frelu(fmaf(y.x, sl[cb],   sl[64+cb])   + xx.x);
    o.y = frelu(fmaf(y.y, sl[cb+1], sl[64+cb+1]) + xx.y);
    o.z = frelu(fmaf(y.z, sl[cb+2], sl[64+cb+2]) + xx.z);
    o.w = frelu(fmaf(y.w, sl[cb+3], sl[64+cb+3]) + xx.w);
    ((float4*)out)[idx] = o;
  }
}

// ---------------------------------------------------------------------------
extern "C" void kernel_launch(void* const* d_in, const int* in_sizes, int n_in,
                              void* d_out, int out_size, void* d_ws, size_t ws_size,
                              hipStream_t stream)
{
  (void)n_in; (void)out_size; (void)ws_size;
  const float* p   = (const float*)d_in[0];
  const float* x   = (const float*)d_in[1];
  const int*   knn = (const int*)  d_in[2];
  const float* W1  = (const float*)d_in[3];
  const float* Wv  = (const float*)d_in[4];
  const float* Wp1 = (const float*)d_in[5];
  const float* Wp2 = (const float*)d_in[6];
  const float* Ww  = (const float*)d_in[7];
  const float* W3  = (const float*)d_in[8];
  const float* g1  = (const float*)d_in[9];
  const float* b1  = (const float*)d_in[10];
  const float* g2  = (const float*)d_in[11];
  const float* b2  = (const float*)d_in[12];
  const float* g3  = (const float*)d_in[13];
  const float* b3  = (const float*)d_in[14];
  const int N = in_sizes[0] / 3;
  const float invN = 1.f / (float)N;

  float* ws = (float*)d_ws;
  float* y        = ws;                        // N*64 (y1, then y3)
  float* v        = y + (size_t)N*64;          // N*64
  float* mixed    = v + (size_t)N*64;          // N*64
  float* hw       = mixed + (size_t)N*64;      // N*8
  float* wp2wT    = hw + (size_t)N*8;          // 512
  float* partials = wp2wT + 512;               // 128*PST
  float* ss1      = partials + (size_t)128*PST;
  float* ss2      = ss1 + 128;
  float* ss3      = ss2 + 128;

  wp2w_k<<<1, 256, 0, stream>>>(Wp2, Ww, wp2wT);
  gemm_mfma_k<0><<<GRID_GEMM, 256, 0, stream>>>(x, W1, nullptr, nullptr, y, nullptr, partials, N);
  fin_k<<<64, 256, 0, stream>>>(partials, GRID_GEMM, g1, b1, ss1, invN);
  gemm_mfma_k<1><<<GRID_GEMM, 256, 0, stream>>>(y, Wv, Ww, ss1, v, hw, nullptr, N);
  mixer_k<<<GRID_MIX, 256, 0, stream>>>(p, knn, v, hw, Wp1, Wp2, wp2wT, mixed, partials, N);
  fin_k<<<64, 256, 0, stream>>>(partials, GRID_MIX, g2, b2, ss2, invN);
  gemm_mfma_k<2><<<GRID_GEMM, 256, 0, stream>>>(mixed, W3, nullptr, ss2, y, nullptr, partials, N);
  fin_k<<<64, 256, 0, stream>>>(partials, GRID_GEMM, g3, b3, ss3, invN);
  final_k<<<GRID_ELT, 256, 0, stream>>>(y, x, ss3, (float*)d_out, N*16);
}

// Round 5
// 207.833 us; speedup vs baseline: 3.3780x; 1.0421x over previous
//
#include <hip/hip_runtime.h>
#include <hip/hip_fp16.h>

#define EPSV 1e-5f
#define PST 2048
#define GRID_GEMM 782
#define GRID_MIX  1280
#define GRID_ELT  1024

typedef _Float16 h2_t __attribute__((ext_vector_type(2)));   // arithmetic
typedef __fp16  fp16x2 __attribute__((ext_vector_type(2)));  // builtin interop
typedef _Float16 f16x8 __attribute__((ext_vector_type(8)));  // MFMA A/B frag
typedef float    f32x4 __attribute__((ext_vector_type(4)));  // MFMA C/D frag
typedef unsigned short u16;

__device__ __forceinline__ float frelu(float x) { return fmaxf(x, 0.f); }

__device__ __forceinline__ float rdl(float v, int l) {
  return __int_as_float(__builtin_amdgcn_readlane(__float_as_int(v), l));
}
__device__ __forceinline__ unsigned int pkrtz(float lo, float hi) {
  fp16x2 h = __builtin_amdgcn_cvt_pkrtz(lo, hi);
  return __builtin_bit_cast(unsigned int, h);
}
__device__ __forceinline__ u16 f16b(float x) {
  return (u16)(pkrtz(x, 0.f) & 0xffffu);
}
__device__ __forceinline__ float fdot2u(unsigned int a, unsigned int b, float c) {
#if __has_builtin(__builtin_amdgcn_fdot2)
  return __builtin_amdgcn_fdot2(__builtin_bit_cast(fp16x2, a),
                                __builtin_bit_cast(fp16x2, b), c, false);
#else
  h2_t ah = __builtin_bit_cast(h2_t, a), bh = __builtin_bit_cast(h2_t, b);
  return c + (float)ah[0]*(float)bh[0] + (float)ah[1]*(float)bh[1];
#endif
}
__device__ __forceinline__ f16x8 mk8(unsigned a, unsigned b, unsigned c, unsigned d) {
  uint4 u; u.x = a; u.y = b; u.z = c; u.w = d;
  return __builtin_bit_cast(f16x8, u);
}
__device__ __forceinline__ f32x4 mfma16(f16x8 a, f16x8 b, f32x4 c) {
  return __builtin_amdgcn_mfma_f32_16x16x32_f16(a, b, c, 0, 0, 0);
}

// ---------------------------------------------------------------------------
// wp2wT[g][a] = sum_c Wp2[a][c] * Ww[c][g]   (8 x 64, fp32)
__global__ __launch_bounds__(256) void wp2w_k(const float* __restrict__ Wp2,
                                             const float* __restrict__ Ww,
                                             float* __restrict__ wp2wT)
{
  const int t = threadIdx.x, a = t >> 2, qq = t & 3;
  float acc[8] = {0,0,0,0,0,0,0,0};
#pragma unroll
  for (int cc = 0; cc < 16; ++cc) {
    const int c = qq*16 + cc;
    const float wv = Wp2[a*64 + c];
#pragma unroll
    for (int g = 0; g < 8; ++g) acc[g] = fmaf(wv, Ww[c*8 + g], acc[g]);
  }
#pragma unroll
  for (int g = 0; g < 8; ++g) {
    acc[g] += __shfl_xor(acc[g], 1);
    acc[g] += __shfl_xor(acc[g], 2);
  }
  if (qq == 0) {
#pragma unroll
    for (int g = 0; g < 8; ++g) wp2wT[g*64 + a] = acc[g];
  }
}

// ---------------------------------------------------------------------------
// MFMA f16 GEMM: out16[N,64](f16) = preop(in) @ W.
// A-frag: row = lane&15, k = 8*(lane>>4)+m.  B-frag: col = lane&15, same k.
// C/D: col = lane&15, row = 4*(lane>>4)+j.
// MODE0: no preop, stats partials. MODE1: preop(ss), + outw16 = preop(in)@Ww.
// MODE2: preop(ss), stats partials.  INF16: input is f16.
template<int MODE, bool INF16>
__global__ __launch_bounds__(256, 4) void gemm_mfma_k(
    const void* __restrict__ in, const float* __restrict__ W,
    const float* __restrict__ Ww, const float* __restrict__ ss,
    u16* __restrict__ out16, u16* __restrict__ outw16,
    float* __restrict__ partials, int N)
{
  __shared__ float red[512];
  __shared__ u16 xh[4][16*72];   // per-wave f16 tile [16 r][72 pad]
  const int t = threadIdx.x, lane = t & 63, w = t >> 6;
  const int r16 = lane & 15, q = lane >> 4;
  u16* const xw = &xh[w][0];

  // --- W fragments (held in VGPRs for the whole kernel) ---
  f16x8 bw[2][4];
#pragma unroll
  for (int kb = 0; kb < 2; ++kb) {
#pragma unroll
    for (int tt = 0; tt < 4; ++tt) {
      const int kbase = 32*kb + 8*q;
      const int cc = 16*tt + r16;
      unsigned u0 = pkrtz(W[(kbase+0)*64 + cc], W[(kbase+1)*64 + cc]);
      unsigned u1 = pkrtz(W[(kbase+2)*64 + cc], W[(kbase+3)*64 + cc]);
      unsigned u2 = pkrtz(W[(kbase+4)*64 + cc], W[(kbase+5)*64 + cc]);
      unsigned u3 = pkrtz(W[(kbase+6)*64 + cc], W[(kbase+7)*64 + cc]);
      bw[kb][tt] = mk8(u0, u1, u2, u3);
    }
  }
  f16x8 bg[2];
  if (MODE == 1) {
#pragma unroll
    for (int kb = 0; kb < 2; ++kb) {
      const int kbase = 32*kb + 8*q;
      unsigned u[4];
#pragma unroll
      for (int mm = 0; mm < 4; ++mm) {
        float g0 = (r16 < 8) ? Ww[(kbase + 2*mm    )*8 + r16] : 0.f;
        float g1 = (r16 < 8) ? Ww[(kbase + 2*mm + 1)*8 + r16] : 0.f;
        u[mm] = pkrtz(g0, g1);
      }
      bg[kb] = mk8(u[0], u[1], u[2], u[3]);
    }
  }
  float sc4[4], sh4[4];
  if (MODE != 0) {
#pragma unroll
    for (int j = 0; j < 4; ++j) {
      sc4[j] = ss[4*r16 + j];
      sh4[j] = ss[64 + 4*r16 + j];
    }
  }

  float S4[4] = {0,0,0,0}, Q4[4] = {0,0,0,0};
  const int ntiles = (N + 15) >> 4;
  for (int tile = blockIdx.x*4 + w; tile < ntiles; tile += GRID_GEMM*4) {
    const int r0 = tile << 4;
    const bool full = (r0 + 16 <= N);
    // --- stage 16x64 -> f16 LDS tile (BN+relu fused, f32 math) ---
#pragma unroll
    for (int i = 0; i < 4; ++i) {
      const int row = q + 4*i;
      float4 xv = {0.f, 0.f, 0.f, 0.f};
      const bool rok = full || (r0 + row < N);
      if (rok) {
        if constexpr (INF16) {
          const uint2 u = *(const uint2*)((const u16*)in + (size_t)(r0 + row)*64 + 4*r16);
          const h2_t lo = __builtin_bit_cast(h2_t, u.x);
          const h2_t hi = __builtin_bit_cast(h2_t, u.y);
          xv.x = (float)lo[0]; xv.y = (float)lo[1];
          xv.z = (float)hi[0]; xv.w = (float)hi[1];
        } else {
          xv = *(const float4*)((const float*)in + (size_t)(r0 + row)*64 + 4*r16);
        }
      }
      if (MODE != 0) {
        xv.x = frelu(fmaf(xv.x, sc4[0], sh4[0]));
        xv.y = frelu(fmaf(xv.y, sc4[1], sh4[1]));
        xv.z = frelu(fmaf(xv.z, sc4[2], sh4[2]));
        xv.w = frelu(fmaf(xv.w, sc4[3], sh4[3]));
        if (!rok) { xv.x = 0.f; xv.y = 0.f; xv.z = 0.f; xv.w = 0.f; }
      }
      uint2 u2v; u2v.x = pkrtz(xv.x, xv.y); u2v.y = pkrtz(xv.z, xv.w);
      *(uint2*)(xw + row*72 + 4*r16) = u2v;
    }
    // --- A fragments ---
    const f16x8 a0 = __builtin_bit_cast(f16x8, *(const uint4*)(xw + r16*72 + 8*q));
    const f16x8 a1 = __builtin_bit_cast(f16x8, *(const uint4*)(xw + r16*72 + 8*q + 32));
    // --- MFMA ---
    f32x4 acc[4];
#pragma unroll
    for (int tt = 0; tt < 4; ++tt) {
      f32x4 z = {0.f, 0.f, 0.f, 0.f};
      z = mfma16(a0, bw[0][tt], z);
      acc[tt] = mfma16(a1, bw[1][tt], z);
    }
    // --- store f16 + stats(f32) ---
#pragma unroll
    for (int tt = 0; tt < 4; ++tt) {
#pragma unroll
      for (int j = 0; j < 4; ++j) {
        if (full || (r0 + 4*q + j < N))
          out16[(size_t)(r0 + 4*q + j)*64 + 16*tt + r16] = f16b(acc[tt][j]);
      }
      if (MODE != 1) {
        S4[tt] += acc[tt][0] + acc[tt][1] + acc[tt][2] + acc[tt][3];
        Q4[tt] = fmaf(acc[tt][0], acc[tt][0], Q4[tt]);
        Q4[tt] = fmaf(acc[tt][1], acc[tt][1], Q4[tt]);
        Q4[tt] = fmaf(acc[tt][2], acc[tt][2], Q4[tt]);
        Q4[tt] = fmaf(acc[tt][3], acc[tt][3], Q4[tt]);
      }
    }
    if (MODE == 1) {
      f32x4 accw = {0.f, 0.f, 0.f, 0.f};
      accw = mfma16(a0, bg[0], accw);
      accw = mfma16(a1, bg[1], accw);
      if (r16 < 8) {
#pragma unroll
        for (int j = 0; j < 4; ++j) {
          if (full || (r0 + 4*q + j < N))
            outw16[(size_t)(r0 + 4*q + j)*8 + r16] = f16b(accw[j]);
        }
      }
    }
  }
  if (MODE != 1) {
#pragma unroll
    for (int tt = 0; tt < 4; ++tt) {
      S4[tt] += __shfl_xor(S4[tt], 16); S4[tt] += __shfl_xor(S4[tt], 32);
      Q4[tt] += __shfl_xor(Q4[tt], 16); Q4[tt] += __shfl_xor(Q4[tt], 32);
    }
    if (lane < 16) {
#pragma unroll
      for (int tt = 0; tt < 4; ++tt) {
        red[w*128 + tt*16 + lane]      = S4[tt];
        red[w*128 + 64 + tt*16 + lane] = Q4[tt];
      }
    }
    __syncthreads();
    if (t < 64) {
      const float s = red[t] + red[128+t] + red[256+t] + red[384+t];
      const float qq = red[64+t] + red[192+t] + red[320+t] + red[448+t];
      partials[(size_t)t*PST + blockIdx.x]      = s;
      partials[(size_t)(64+t)*PST + blockIdx.x] = qq;
    }
  }
}

// ---------------------------------------------------------------------------
// 64-block finalize: block c reads its two coalesced partial rows.
__global__ __launch_bounds__(256) void fin_k(const float* __restrict__ partials,
    int nblk, const float* __restrict__ gamma, const float* __restrict__ beta,
    float* __restrict__ ss, float invN)
{
  __shared__ float red[8];
  const int c = blockIdx.x;
  float s = 0.f, q = 0.f;
  for (int i = threadIdx.x; i < nblk; i += 256) {
    s += partials[(size_t)c*PST + i];
    q += partials[(size_t)(64+c)*PST + i];
  }
#pragma unroll
  for (int mk = 1; mk < 64; mk <<= 1) {
    s += __shfl_xor(s, mk);
    q += __shfl_xor(q, mk);
  }
  const int w = threadIdx.x >> 6;
  if ((threadIdx.x & 63) == 0) { red[w*2] = s; red[w*2+1] = q; }
  __syncthreads();
  if (threadIdx.x == 0) {
    const float S = red[0]+red[2]+red[4]+red[6];
    const float Q = red[1]+red[3]+red[5]+red[7];
    const float mean = S*invN;
    const float var  = Q*invN - mean*mean;
    const float scale = gamma[c] * rsqrtf(var + EPSV);
    ss[c] = scale; ss[64+c] = beta[c] - mean*scale;
  }
}

// ---------------------------------------------------------------------------
// Wave-per-point mixer, f16 e-path + f16 gathers. LDS 27.8KB -> 5 blocks/CU.
__global__ __launch_bounds__(256, 4) void mixer_k(
    const float* __restrict__ p, const int* __restrict__ knn,
    const u16* __restrict__ v16, const u16* __restrict__ hw16,
    const float* __restrict__ Wp1, const float* __restrict__ Wp2,
    const float* __restrict__ wp2wT, u16* __restrict__ mx16,
    float* __restrict__ partials, int N)
{
  __shared__ unsigned int lds[6944];
  unsigned int* const Wp2h = lds;            // [64 c][36] f16 pairs over d
  unsigned int* const wwh  = lds + 2304;     // [8 g][36] f16 pairs over d
  const int t = threadIdx.x, lane = t & 63, w = t >> 6;
  unsigned int* const wb   = lds + 2592 + w*960;
  unsigned int* const e_h  = wb;             // [16 k][36] f16 pairs over d
  unsigned int* const wh_s = wb + 576;       // [16 k][4]  f16 pairs over g
  unsigned int* const S_h  = wb + 640;       // [8 g][36]  f16 pairs over d
  int*          const j_s  = (int*)(wb + 928);   // [16]
  float*        const red  = (float*)(lds + 2592 + 4*960); // [512]

  for (int idx = t; idx < 2048; idx += 256) {
    const int m = idx >> 6, c = idx & 63;
    Wp2h[c*36 + m] = pkrtz(Wp2[(2*m)*64 + c], Wp2[(2*m+1)*64 + c]);
  }
  {
    const int g = t >> 5, m = t & 31;
    if (t < 256) wwh[g*36 + m] = pkrtz(wp2wT[g*64 + 2*m], wp2wT[g*64 + 2*m+1]);
  }
  __syncthreads();

  const float w1x = Wp1[lane], w1y = Wp1[64+lane], w1z = Wp1[128+lane];
  const int kb = lane >> 2, gg = lane & 3;
  const int g8 = lane >> 3;
  const unsigned int wsh = (unsigned)(g8 & 1) * 16u;
  const int wcol = g8 >> 1;
  const bool evenl = ((lane & 1) == 0);
  float ssum = 0.f, sq = 0.f;
  const int nwaves = gridDim.x * 4;

  for (int i = blockIdx.x*4 + w; i < N; i += nwaves) {
    float dx = 0.f, dy = 0.f, dz = 0.f;
    int jreg = 0;
    if (lane < 16) {
      jreg = knn[(size_t)i*16 + lane];
      j_s[lane] = jreg;
      dx = p[(size_t)jreg*3]   - p[(size_t)i*3];
      dy = p[(size_t)jreg*3+1] - p[(size_t)i*3+1];
      dz = p[(size_t)jreg*3+2] - p[(size_t)i*3+2];
    }
    // ---- Phase A: e'[k] per lane=d (deltas broadcast via readlane)
    float ep[16];
#pragma unroll
    for (int k = 0; k < 16; ++k) {
      ep[k] = frelu(fmaf(rdl(dx,k), w1x, fmaf(rdl(dy,k), w1y, rdl(dz,k)*w1z)));
    }
#pragma unroll
    for (int k = 0; k < 16; k += 2) {
      const float n0 = __shfl_xor(ep[k], 1);
      const float n1 = __shfl_xor(ep[k+1], 1);
      const float lo = evenl ? ep[k] : n1;
      const float hi = evenl ? n0 : ep[k+1];
      const int row = k + (evenl ? 0 : 1);
      e_h[row*36 + (lane>>1)] = pkrtz(lo, hi);
    }
    // ---- Phase B: energies for (kb, g=2gg,2gg+1) via fdot2
    const int jb = j_s[kb];
    const unsigned int hwu = *(const unsigned int*)(hw16 + (size_t)jb*8 + 2*gg);
    const h2_t hv = __builtin_bit_cast(h2_t, hwu);
    float en0 = (float)hv[0], en1 = (float)hv[1];
    const unsigned int* erow = e_h + kb*36;
    const unsigned int* wr0  = wwh + (2*gg)*36;
    const unsigned int* wr1  = wwh + (2*gg+1)*36;
#pragma unroll
    for (int m4 = 0; m4 < 8; ++m4) {
      const uint4 e4 = *(const uint4*)(erow + m4*4);
      const uint4 a0 = *(const uint4*)(wr0 + m4*4);
      const uint4 a1 = *(const uint4*)(wr1 + m4*4);
      en0 = fdot2u(e4.x, a0.x, en0); en1 = fdot2u(e4.x, a1.x, en1);
      en0 = fdot2u(e4.y, a0.y, en0); en1 = fdot2u(e4.y, a1.y, en1);
      en0 = fdot2u(e4.z, a0.z, en0); en1 = fdot2u(e4.z, a1.z, en1);
      en0 = fdot2u(e4.w, a0.w, en0); en1 = fdot2u(e4.w, a1.w, en1);
    }
    // softmax over k (lanes stride 4)
    float m0 = en0, m1 = en1;
#pragma unroll
    for (int mk = 4; mk < 64; mk <<= 1) {
      m0 = fmaxf(m0, __shfl_xor(m0, mk));
      m1 = fmaxf(m1, __shfl_xor(m1, mk));
    }
    const float p0 = __expf(en0 - m0), p1 = __expf(en1 - m1);
    float s0 = p0, s1 = p1;
#pragma unroll
    for (int mk = 4; mk < 64; mk <<= 1) {
      s0 += __shfl_xor(s0, mk);
      s1 += __shfl_xor(s1, mk);
    }
    wh_s[kb*4 + gg] = pkrtz(p0/s0, p1/s1);
    // ---- Phase S: S[g][d=lane] = sum_k w[k][g] * e'[k][d]  (pk_fma_f16)
    h2_t S2[4];
#pragma unroll
    for (int j2 = 0; j2 < 4; ++j2) S2[j2] = h2_t{(_Float16)0.f, (_Float16)0.f};
#pragma unroll
    for (int k = 0; k < 16; ++k) {
      const uint4 wk = *(const uint4*)(wh_s + k*4);
      const h2_t e2 = __builtin_bit_cast(h2_t, pkrtz(ep[k], ep[k]));
      S2[0] = __builtin_bit_cast(h2_t, wk.x) * e2 + S2[0];
      S2[1] = __builtin_bit_cast(h2_t, wk.y) * e2 + S2[1];
      S2[2] = __builtin_bit_cast(h2_t, wk.z) * e2 + S2[2];
      S2[3] = __builtin_bit_cast(h2_t, wk.w) * e2 + S2[3];
    }
#pragma unroll
    for (int j2 = 0; j2 < 4; ++j2) {
      const unsigned int own = __builtin_bit_cast(unsigned int, S2[j2]);
      const unsigned int nb = (unsigned int)__shfl_xor((int)own, 1);
      const unsigned int u = evenl ? ((own & 0xffffu) | (nb << 16))
                                   : ((nb >> 16) | (own & 0xffff0000u));
      const int row = 2*j2 + (evenl ? 0 : 1);
      S_h[row*36 + (lane>>1)] = u;
    }
    // ---- vsum: f16 random v-row gathers (128B/row), w from f16 LDS
    float acc = 0.f;
#pragma unroll
    for (int k = 0; k < 16; ++k) {
      const int jk = __builtin_amdgcn_readlane(jreg, k);
      const float vv = (float)(*(const _Float16*)(v16 + (size_t)jk*64 + lane));
      const unsigned int wk = wh_s[k*4 + wcol];
      const h2_t wh = __builtin_bit_cast(h2_t, wk >> wsh);
      acc = fmaf((float)wh[0], vv, acc);
    }
    // ---- e-part: acc += sum_d S[g8][d] * Wp2[d][c=lane]
    const unsigned int* srow = S_h + g8*36;
    const unsigned int* prow = Wp2h + lane*36;
#pragma unroll
    for (int m4 = 0; m4 < 8; ++m4) {
      const uint4 s4 = *(const uint4*)(srow + m4*4);
      const uint4 wp = *(const uint4*)(prow + m4*4);
      acc = fdot2u(s4.x, wp.x, acc);
      acc = fdot2u(s4.y, wp.y, acc);
      acc = fdot2u(s4.z, wp.z, acc);
      acc = fdot2u(s4.w, wp.w, acc);
    }
    mx16[(size_t)i*64 + lane] = f16b(acc);
    ssum += acc; sq = fmaf(acc, acc, sq);
  }
  __syncthreads();
  red[w*128 + lane] = ssum; red[w*128 + 64 + lane] = sq;
  __syncthreads();
  if (t < 64) {
    const float s = red[t] + red[128+t] + red[256+t] + red[384+t];
    const float q = red[64+t] + red[192+t] + red[320+t] + red[448+t];
    partials[(size_t)t*PST + blockIdx.x]      = s;
    partials[(size_t)(64+t)*PST + blockIdx.x] = q;
  }
}

// ---------------------------------------------------------------------------
__global__ __launch_bounds__(256) void final_k(const u16* __restrict__ y16,
    const float* __restrict__ x, const float* __restrict__ ss,
    float* __restrict__ out, int n4)
{
  __shared__ float sl[128];
  if (threadIdx.x < 128) sl[threadIdx.x] = ss[threadIdx.x];
  __syncthreads();
  for (int idx = blockIdx.x*256 + threadIdx.x; idx < n4; idx += gridDim.x*256) {
    const int cb = (idx & 15) << 2;
    const uint2 yu = *(const uint2*)(y16 + (size_t)idx*4);
    const h2_t ylo = __builtin_bit_cast(h2_t, yu.x);
    const h2_t yhi = __builtin_bit_cast(h2_t, yu.y);
    const float4 xx = ((const float4*)x)[idx];
    float4 o;
    o.x = frelu(fmaf((float)ylo[0], sl[cb],   sl[64+cb])   + xx.x);
    o.y = frelu(fmaf((float)ylo[1], sl[cb+1], sl[64+cb+1]) + xx.y);
    o.z = frelu(fmaf((float)yhi[0], sl[cb+2], sl[64+cb+2]) + xx.z);
    o.w = frelu(fmaf((float)yhi[1], sl[cb+3], sl[64+cb+3]) + xx.w);
    ((float4*)out)[idx] = o;
  }
}

// ---------------------------------------------------------------------------
extern "C" void kernel_launch(void* const* d_in, const int* in_sizes, int n_in,
                              void* d_out, int out_size, void* d_ws, size_t ws_size,
                              hipStream_t stream)
{
  (void)n_in; (void)out_size; (void)ws_size;
  const float* p   = (const float*)d_in[0];
  const float* x   = (const float*)d_in[1];
  const int*   knn = (const int*)  d_in[2];
  const float* W1  = (const float*)d_in[3];
  const float* Wv  = (const float*)d_in[4];
  const float* Wp1 = (const float*)d_in[5];
  const float* Wp2 = (const float*)d_in[6];
  const float* Ww  = (const float*)d_in[7];
  const float* W3  = (const float*)d_in[8];
  const float* g1  = (const float*)d_in[9];
  const float* b1  = (const float*)d_in[10];
  const float* g2  = (const float*)d_in[11];
  const float* b2  = (const float*)d_in[12];
  const float* g3  = (const float*)d_in[13];
  const float* b3  = (const float*)d_in[14];
  const int N = in_sizes[0] / 3;
  const float invN = 1.f / (float)N;

  u16* ws16 = (u16*)d_ws;
  u16* y16   = ws16;                       // N*64 f16 (y1, then y3)
  u16* v16   = y16 + (size_t)N*64;         // N*64 f16
  u16* mx16  = v16 + (size_t)N*64;         // N*64 f16
  u16* hw16  = mx16 + (size_t)N*64;        // N*8 f16
  float* wp2wT    = (float*)(hw16 + (size_t)N*8);   // 512 f32
  float* partials = wp2wT + 512;           // 128*PST
  float* ss1      = partials + (size_t)128*PST;
  float* ss2      = ss1 + 128;
  float* ss3      = ss2 + 128;

  wp2w_k<<<1, 256, 0, stream>>>(Wp2, Ww, wp2wT);
  gemm_mfma_k<0, false><<<GRID_GEMM, 256, 0, stream>>>(x, W1, nullptr, nullptr, y16, nullptr, partials, N);
  fin_k<<<64, 256, 0, stream>>>(partials, GRID_GEMM, g1, b1, ss1, invN);
  gemm_mfma_k<1, true><<<GRID_GEMM, 256, 0, stream>>>(y16, Wv, Ww, ss1, v16, hw16, nullptr, N);
  mixer_k<<<GRID_MIX, 256, 0, stream>>>(p, knn, v16, hw16, Wp1, Wp2, wp2wT, mx16, partials, N);
  fin_k<<<64, 256, 0, stream>>>(partials, GRID_MIX, g2, b2, ss2, invN);
  gemm_mfma_k<2, true><<<GRID_GEMM, 256, 0, stream>>>(mx16, W3, nullptr, ss2, y16, nullptr, partials, N);
  fin_k<<<64, 256, 0, stream>>>(partials, GRID_GEMM, g3, b3, ss3, invN);
  final_k<<<GRID_ELT, 256, 0, stream>>>(y16, x, ss3, (float*)d_out, N*16);
}

// Round 8
// 119.708 us; speedup vs baseline: 5.8647x; 1.7362x over previous
//
#include <hip/hip_runtime.h>
#include <hip/hip_fp16.h>

#define EPSV 1e-5f
#define PST 2048
#define GRID_GEMM 782
#define GRID_MIX  1024
#define GRID_ELT  1024

typedef _Float16 h2_t  __attribute__((ext_vector_type(2)));  // packed arithmetic
typedef __fp16   fp16x2 __attribute__((ext_vector_type(2))); // builtin interop
typedef _Float16 f16x4 __attribute__((ext_vector_type(4)));  // MFMA K=16 A/B frag
typedef _Float16 f16x8 __attribute__((ext_vector_type(8)));  // MFMA K=32 A/B frag
typedef float    f32x4 __attribute__((ext_vector_type(4)));  // MFMA C/D frag
typedef unsigned short u16;

__device__ __forceinline__ float frelu(float x) { return fmaxf(x, 0.f); }

__device__ __forceinline__ unsigned int pkrtz(float lo, float hi) {
  fp16x2 h = __builtin_amdgcn_cvt_pkrtz(lo, hi);
  return __builtin_bit_cast(unsigned int, h);
}
__device__ __forceinline__ u16 f16b(float x) {
  return (u16)(pkrtz(x, 0.f) & 0xffffu);
}
__device__ __forceinline__ float f16tof(u16 u) {
  return (float)(*reinterpret_cast<const _Float16*>(&u));
}
__device__ __forceinline__ f16x8 mk8(unsigned a, unsigned b, unsigned c, unsigned d) {
  uint4 u; u.x = a; u.y = b; u.z = c; u.w = d;
  return __builtin_bit_cast(f16x8, u);
}
__device__ __forceinline__ f16x4 mk4(unsigned a, unsigned b) {
  uint2 u; u.x = a; u.y = b;
  return __builtin_bit_cast(f16x4, u);
}
__device__ __forceinline__ f32x4 mfma16(f16x8 a, f16x8 b, f32x4 c) {
  return __builtin_amdgcn_mfma_f32_16x16x32_f16(a, b, c, 0, 0, 0);
}
__device__ __forceinline__ f32x4 mfma16k16(f16x4 a, f16x4 b, f32x4 c) {
  return __builtin_amdgcn_mfma_f32_16x16x16f16(a, b, c, 0, 0, 0);
}
// packed f16 relu via sign-bit masking (no __half2 header dependency):
// each half with sign bit set -> 0.
__device__ __forceinline__ unsigned relu2(unsigned u) {
  const unsigned m = ((u & 0x80008000u) >> 15) * 0xFFFFu;
  return u & ~m;
}

// ---------------------------------------------------------------------------
// Pack ww = Wp2@Ww, Wp2, Wp1 into MFMA fragment-layout constant buffers.
// wwf [2 half][64 lane]   : B[col=g(<8)][kd=32h+8q+m] = ww[d][g]
// wp2f[4 tt][2 half][64]  : B[col=16tt+r16][kd=32h+8q+m] = Wp2[d][c]
// w1f [3 r][2 half][64]   : pairs Wp1[r][32h+8q+2mm .. +1]
__global__ __launch_bounds__(256) void pack_k(
    const float* __restrict__ Wp2, const float* __restrict__ Ww,
    const float* __restrict__ Wp1,
    uint4* __restrict__ wwf, uint4* __restrict__ wp2f, uint4* __restrict__ w1f)
{
  __shared__ float wwl[512];   // ww[d][g] = sum_c Wp2[d][c]*Ww[c][g]
  const int t = threadIdx.x, a = t >> 2, qq = t & 3;
  float acc[8] = {0,0,0,0,0,0,0,0};
#pragma unroll
  for (int cc = 0; cc < 16; ++cc) {
    const int c = qq*16 + cc;
    const float wv = Wp2[a*64 + c];
#pragma unroll
    for (int g = 0; g < 8; ++g) acc[g] = fmaf(wv, Ww[c*8 + g], acc[g]);
  }
#pragma unroll
  for (int g = 0; g < 8; ++g) {
    acc[g] += __shfl_xor(acc[g], 1);
    acc[g] += __shfl_xor(acc[g], 2);
  }
  if (qq == 0) {
#pragma unroll
    for (int g = 0; g < 8; ++g) wwl[a*8 + g] = acc[g];
  }
  __syncthreads();
  if (t < 128) {
    const int h = t >> 6, l = t & 63, r16 = l & 15, q = l >> 4;
    uint4 u = {0,0,0,0};
    if (r16 < 8) {
      unsigned c0 = pkrtz(wwl[(32*h+8*q+0)*8 + r16], wwl[(32*h+8*q+1)*8 + r16]);
      unsigned c1 = pkrtz(wwl[(32*h+8*q+2)*8 + r16], wwl[(32*h+8*q+3)*8 + r16]);
      unsigned c2 = pkrtz(wwl[(32*h+8*q+4)*8 + r16], wwl[(32*h+8*q+5)*8 + r16]);
      unsigned c3 = pkrtz(wwl[(32*h+8*q+6)*8 + r16], wwl[(32*h+8*q+7)*8 + r16]);
      u.x = c0; u.y = c1; u.z = c2; u.w = c3;
    }
    wwf[t] = u;
  }
  for (int e = t; e < 512; e += 256) {
    const int tt = e >> 7, h = (e >> 6) & 1, l = e & 63;
    const int c = 16*tt + (l & 15), q = l >> 4;
    const int d0 = 32*h + 8*q;
    uint4 u;
    u.x = pkrtz(Wp2[(d0+0)*64 + c], Wp2[(d0+1)*64 + c]);
    u.y = pkrtz(Wp2[(d0+2)*64 + c], Wp2[(d0+3)*64 + c]);
    u.z = pkrtz(Wp2[(d0+4)*64 + c], Wp2[(d0+5)*64 + c]);
    u.w = pkrtz(Wp2[(d0+6)*64 + c], Wp2[(d0+7)*64 + c]);
    wp2f[e] = u;
  }
  for (int e = t; e < 384; e += 256) {
    const int r = e >> 7, h = (e >> 6) & 1, l = e & 63, q = l >> 4;
    const int d0 = 32*h + 8*q;
    uint4 u;
    u.x = pkrtz(Wp1[r*64 + d0+0], Wp1[r*64 + d0+1]);
    u.y = pkrtz(Wp1[r*64 + d0+2], Wp1[r*64 + d0+3]);
    u.z = pkrtz(Wp1[r*64 + d0+4], Wp1[r*64 + d0+5]);
    u.w = pkrtz(Wp1[r*64 + d0+6], Wp1[r*64 + d0+7]);
    w1f[e] = u;
  }
}

// ---------------------------------------------------------------------------
// MFMA f16 GEMM (unchanged from R5): out16[N,64](f16) = preop(in) @ W.
template<int MODE, bool INF16>
__global__ __launch_bounds__(256, 4) void gemm_mfma_k(
    const void* __restrict__ in, const float* __restrict__ W,
    const float* __restrict__ Ww, const float* __restrict__ ss,
    u16* __restrict__ out16, u16* __restrict__ outw16,
    float* __restrict__ partials, int N)
{
  __shared__ float red[512];
  __shared__ u16 xh[4][16*72];
  const int t = threadIdx.x, lane = t & 63, w = t >> 6;
  const int r16 = lane & 15, q = lane >> 4;
  u16* const xw = &xh[w][0];

  f16x8 bw[2][4];
#pragma unroll
  for (int kb = 0; kb < 2; ++kb) {
#pragma unroll
    for (int tt = 0; tt < 4; ++tt) {
      const int kbase = 32*kb + 8*q;
      const int cc = 16*tt + r16;
      unsigned u0 = pkrtz(W[(kbase+0)*64 + cc], W[(kbase+1)*64 + cc]);
      unsigned u1 = pkrtz(W[(kbase+2)*64 + cc], W[(kbase+3)*64 + cc]);
      unsigned u2 = pkrtz(W[(kbase+4)*64 + cc], W[(kbase+5)*64 + cc]);
      unsigned u3 = pkrtz(W[(kbase+6)*64 + cc], W[(kbase+7)*64 + cc]);
      bw[kb][tt] = mk8(u0, u1, u2, u3);
    }
  }
  f16x8 bg[2];
  if (MODE == 1) {
#pragma unroll
    for (int kb = 0; kb < 2; ++kb) {
      const int kbase = 32*kb + 8*q;
      unsigned u[4];
#pragma unroll
      for (int mm = 0; mm < 4; ++mm) {
        float g0 = (r16 < 8) ? Ww[(kbase + 2*mm    )*8 + r16] : 0.f;
        float g1 = (r16 < 8) ? Ww[(kbase + 2*mm + 1)*8 + r16] : 0.f;
        u[mm] = pkrtz(g0, g1);
      }
      bg[kb] = mk8(u[0], u[1], u[2], u[3]);
    }
  }
  float sc4[4], sh4[4];
  if (MODE != 0) {
#pragma unroll
    for (int j = 0; j < 4; ++j) {
      sc4[j] = ss[4*r16 + j];
      sh4[j] = ss[64 + 4*r16 + j];
    }
  }

  float S4[4] = {0,0,0,0}, Q4[4] = {0,0,0,0};
  const int ntiles = (N + 15) >> 4;
  for (int tile = blockIdx.x*4 + w; tile < ntiles; tile += GRID_GEMM*4) {
    const int r0 = tile << 4;
    const bool full = (r0 + 16 <= N);
#pragma unroll
    for (int i = 0; i < 4; ++i) {
      const int row = q + 4*i;
      float4 xv = {0.f, 0.f, 0.f, 0.f};
      const bool rok = full || (r0 + row < N);
      if (rok) {
        if constexpr (INF16) {
          const uint2 u = *(const uint2*)((const u16*)in + (size_t)(r0 + row)*64 + 4*r16);
          const h2_t lo = __builtin_bit_cast(h2_t, u.x);
          const h2_t hi = __builtin_bit_cast(h2_t, u.y);
          xv.x = (float)lo[0]; xv.y = (float)lo[1];
          xv.z = (float)hi[0]; xv.w = (float)hi[1];
        } else {
          xv = *(const float4*)((const float*)in + (size_t)(r0 + row)*64 + 4*r16);
        }
      }
      if (MODE != 0) {
        xv.x = frelu(fmaf(xv.x, sc4[0], sh4[0]));
        xv.y = frelu(fmaf(xv.y, sc4[1], sh4[1]));
        xv.z = frelu(fmaf(xv.z, sc4[2], sh4[2]));
        xv.w = frelu(fmaf(xv.w, sc4[3], sh4[3]));
        if (!rok) { xv.x = 0.f; xv.y = 0.f; xv.z = 0.f; xv.w = 0.f; }
      }
      uint2 u2v; u2v.x = pkrtz(xv.x, xv.y); u2v.y = pkrtz(xv.z, xv.w);
      *(uint2*)(xw + row*72 + 4*r16) = u2v;
    }
    const f16x8 a0 = __builtin_bit_cast(f16x8, *(const uint4*)(xw + r16*72 + 8*q));
    const f16x8 a1 = __builtin_bit_cast(f16x8, *(const uint4*)(xw + r16*72 + 8*q + 32));
    f32x4 acc[4];
#pragma unroll
    for (int tt = 0; tt < 4; ++tt) {
      f32x4 z = {0.f, 0.f, 0.f, 0.f};
      z = mfma16(a0, bw[0][tt], z);
      acc[tt] = mfma16(a1, bw[1][tt], z);
    }
#pragma unroll
    for (int tt = 0; tt < 4; ++tt) {
#pragma unroll
      for (int j = 0; j < 4; ++j) {
        if (full || (r0 + 4*q + j < N))
          out16[(size_t)(r0 + 4*q + j)*64 + 16*tt + r16] = f16b(acc[tt][j]);
      }
      if (MODE != 1) {
        S4[tt] += acc[tt][0] + acc[tt][1] + acc[tt][2] + acc[tt][3];
        Q4[tt] = fmaf(acc[tt][0], acc[tt][0], Q4[tt]);
        Q4[tt] = fmaf(acc[tt][1], acc[tt][1], Q4[tt]);
        Q4[tt] = fmaf(acc[tt][2], acc[tt][2], Q4[tt]);
        Q4[tt] = fmaf(acc[tt][3], acc[tt][3], Q4[tt]);
      }
    }
    if (MODE == 1) {
      f32x4 accw = {0.f, 0.f, 0.f, 0.f};
      accw = mfma16(a0, bg[0], accw);
      accw = mfma16(a1, bg[1], accw);
      if (r16 < 8) {
#pragma unroll
        for (int j = 0; j < 4; ++j) {
          if (full || (r0 + 4*q + j < N))
            outw16[(size_t)(r0 + 4*q + j)*8 + r16] = f16b(accw[j]);
        }
      }
    }
  }
  if (MODE != 1) {
#pragma unroll
    for (int tt = 0; tt < 4; ++tt) {
      S4[tt] += __shfl_xor(S4[tt], 16); S4[tt] += __shfl_xor(S4[tt], 32);
      Q4[tt] += __shfl_xor(Q4[tt], 16); Q4[tt] += __shfl_xor(Q4[tt], 32);
    }
    if (lane < 16) {
#pragma unroll
      for (int tt = 0; tt < 4; ++tt) {
        red[w*128 + tt*16 + lane]      = S4[tt];
        red[w*128 + 64 + tt*16 + lane] = Q4[tt];
      }
    }
    __syncthreads();
    if (t < 64) {
      const float s = red[t] + red[128+t] + red[256+t] + red[384+t];
      const float qq = red[64+t] + red[192+t] + red[320+t] + red[448+t];
      partials[(size_t)t*PST + blockIdx.x]      = s;
      partials[(size_t)(64+t)*PST + blockIdx.x] = qq;
    }
  }
}

// ---------------------------------------------------------------------------
__global__ __launch_bounds__(256) void fin_k(const float* __restrict__ partials,
    int nblk, const float* __restrict__ gamma, const float* __restrict__ beta,
    float* __restrict__ ss, float invN)
{
  __shared__ float red[8];
  const int c = blockIdx.x;
  float s = 0.f, q = 0.f;
  for (int i = threadIdx.x; i < nblk; i += 256) {
    s += partials[(size_t)c*PST + i];
    q += partials[(size_t)(64+c)*PST + i];
  }
#pragma unroll
  for (int mk = 1; mk < 64; mk <<= 1) {
    s += __shfl_xor(s, mk);
    q += __shfl_xor(q, mk);
  }
  const int w = threadIdx.x >> 6;
  if ((threadIdx.x & 63) == 0) { red[w*2] = s; red[w*2+1] = q; }
  __syncthreads();
  if (threadIdx.x == 0) {
    const float S = red[0]+red[2]+red[4]+red[6];
    const float Q = red[1]+red[3]+red[5]+red[7];
    const float mean = S*invN;
    const float var  = Q*invN - mean*mean;
    const float scale = gamma[c] * rsqrtf(var + EPSV);
    ss[c] = scale; ss[64+c] = beta[c] - mean*scale;
  }
}

// ---------------------------------------------------------------------------
// MFMA mixer: one wave per point, zero LDS in the hot path.
// lane roles: r16 = lane&15, q = lane>>4.
// e' A-frag[row=k=r16][kd=d=32h+8q+m];  energy C[row=k=4q+j][col=g=r16];
// w->A-frag & E->B-frag conversions are lane-local cvt_pk (K=16 identity).
__global__ __launch_bounds__(256, 4) void mixer_k(
    const float* __restrict__ p, const int* __restrict__ knn,
    const u16* __restrict__ v16, const u16* __restrict__ hw16,
    const uint4* __restrict__ wwf, const uint4* __restrict__ wp2f,
    const uint4* __restrict__ w1f,
    u16* __restrict__ mx16, float* __restrict__ partials, int N)
{
  __shared__ float red[512];
  const int t = threadIdx.x, lane = t & 63, w = t >> 6;
  const int r16 = lane & 15, q = lane >> 4, b = r16 >> 3;

  // constants in VGPRs
  f16x8 wwB[2];
  wwB[0] = __builtin_bit_cast(f16x8, wwf[lane]);
  wwB[1] = __builtin_bit_cast(f16x8, wwf[64 + lane]);
  f16x8 wp2B[8];
#pragma unroll
  for (int e = 0; e < 8; ++e)
    wp2B[e] = __builtin_bit_cast(f16x8, wp2f[e*64 + lane]);
  unsigned w1a[6][4];
#pragma unroll
  for (int e = 0; e < 6; ++e) {
    const uint4 u = w1f[e*64 + lane];
    w1a[e][0] = u.x; w1a[e][1] = u.y; w1a[e][2] = u.z; w1a[e][3] = u.w;
  }

  float ssum = 0.f, sq = 0.f;
  const int nwaves = gridDim.x * 4;

  for (int i = blockIdx.x*4 + w; i < N; i += nwaves) {
    // ---- gathers (issued early; vmem pipe) ----
    const int4 kn4 = *(const int4*)(knn + (size_t)i*16 + 4*q);
    const int kn[4] = {kn4.x, kn4.y, kn4.z, kn4.w};
    const int jj = knn[(size_t)i*16 + r16];
    u16 vt[4][4];
#pragma unroll
    for (int tt = 0; tt < 4; ++tt)
#pragma unroll
      for (int j = 0; j < 4; ++j)
        vt[tt][j] = v16[(size_t)kn[j]*64 + 16*tt + r16];
    u16 hvu[4];
#pragma unroll
    for (int j = 0; j < 4; ++j) hvu[j] = hw16[(size_t)kn[j]*8 + r16];
    const float pix = p[(size_t)i*3], piy = p[(size_t)i*3+1], piz = p[(size_t)i*3+2];
    const float dx = p[(size_t)jj*3]   - pix;
    const float dy = p[(size_t)jj*3+1] - piy;
    const float dz = p[(size_t)jj*3+2] - piz;

    // ---- e' fragments (packed f16, zero LDS) ----
    const h2_t dx2 = __builtin_bit_cast(h2_t, pkrtz(dx, dx));
    const h2_t dy2 = __builtin_bit_cast(h2_t, pkrtz(dy, dy));
    const h2_t dz2 = __builtin_bit_cast(h2_t, pkrtz(dz, dz));
    f16x8 eA[2];
#pragma unroll
    for (int h = 0; h < 2; ++h) {
      unsigned eu[4];
#pragma unroll
      for (int mm = 0; mm < 4; ++mm) {
        h2_t acc = dz2 * __builtin_bit_cast(h2_t, w1a[4+h][mm]);
        acc = dy2 * __builtin_bit_cast(h2_t, w1a[2+h][mm]) + acc;
        acc = dx2 * __builtin_bit_cast(h2_t, w1a[0+h][mm]) + acc;
        eu[mm] = relu2(__builtin_bit_cast(unsigned, acc));
      }
      eA[h] = mk8(eu[0], eu[1], eu[2], eu[3]);
    }

    // ---- energy[k][g] via MFMA + hw bias ----
    f32x4 en = {0.f, 0.f, 0.f, 0.f};
    en = mfma16(eA[0], wwB[0], en);
    en = mfma16(eA[1], wwB[1], en);
#pragma unroll
    for (int j = 0; j < 4; ++j)
      en[j] += (r16 < 8) ? f16tof(hvu[j]) : 0.f;

    // ---- softmax over k (regs + cross-q) ----
    float m = fmaxf(fmaxf(en[0], en[1]), fmaxf(en[2], en[3]));
    m = fmaxf(m, __shfl_xor(m, 16));
    m = fmaxf(m, __shfl_xor(m, 32));
    const float e0 = __expf(en[0]-m), e1 = __expf(en[1]-m);
    const float e2 = __expf(en[2]-m), e3 = __expf(en[3]-m);
    float s = e0 + e1 + e2 + e3;
    s += __shfl_xor(s, 16);
    s += __shfl_xor(s, 32);
    const float rs = 1.f / s;
    const f16x4 aw = mk4(pkrtz(e0*rs, e1*rs), pkrtz(e2*rs, e3*rs));

    // ---- per c-tile: E = e'@Wp2 (+V), then G = w@(V+E), extract ----
    float outv = 0.f;
#pragma unroll
    for (int tt = 0; tt < 4; ++tt) {
      f32x4 E = {0.f, 0.f, 0.f, 0.f};
      E = mfma16(eA[0], wp2B[tt*2], E);
      E = mfma16(eA[1], wp2B[tt*2+1], E);
#pragma unroll
      for (int j = 0; j < 4; ++j) E[j] += f16tof(vt[tt][j]);
      const f16x4 bE = mk4(pkrtz(E[0], E[1]), pkrtz(E[2], E[3]));
      f32x4 G = {0.f, 0.f, 0.f, 0.f};
      G = mfma16k16(aw, bE, G);
      const float sel = b ? G[(2*tt+1) & 3] : G[(2*tt) & 3];
      const float val = __shfl(sel, ((tt >= 2) ? 16 : 0) + r16);
      if (q == tt) outv = val;
    }
    mx16[(size_t)i*64 + lane] = f16b(outv);
    ssum += outv; sq = fmaf(outv, outv, sq);
  }
  __syncthreads();
  red[w*128 + lane] = ssum; red[w*128 + 64 + lane] = sq;
  __syncthreads();
  if (t < 64) {
    const float s = red[t] + red[128+t] + red[256+t] + red[384+t];
    const float qv = red[64+t] + red[192+t] + red[320+t] + red[448+t];
    partials[(size_t)t*PST + blockIdx.x]      = s;
    partials[(size_t)(64+t)*PST + blockIdx.x] = qv;
  }
}

// ---------------------------------------------------------------------------
__global__ __launch_bounds__(256) void final_k(const u16* __restrict__ y16,
    const float* __restrict__ x, const float* __restrict__ ss,
    float* __restrict__ out, int n4)
{
  __shared__ float sl[128];
  if (threadIdx.x < 128) sl[threadIdx.x] = ss[threadIdx.x];
  __syncthreads();
  for (int idx = blockIdx.x*256 + threadIdx.x; idx < n4; idx += gridDim.x*256) {
    const int cb = (idx & 15) << 2;
    const uint2 yu = *(const uint2*)(y16 + (size_t)idx*4);
    const h2_t ylo = __builtin_bit_cast(h2_t, yu.x);
    const h2_t yhi = __builtin_bit_cast(h2_t, yu.y);
    const float4 xx = ((const float4*)x)[idx];
    float4 o;
    o.x = frelu(fmaf((float)ylo[0], sl[cb],   sl[64+cb])   + xx.x);
    o.y = frelu(fmaf((float)ylo[1], sl[cb+1], sl[64+cb+1]) + xx.y);
    o.z = frelu(fmaf((float)yhi[0], sl[cb+2], sl[64+cb+2]) + xx.z);
    o.w = frelu(fmaf((float)yhi[1], sl[cb+3], sl[64+cb+3]) + xx.w);
    ((float4*)out)[idx] = o;
  }
}

// ---------------------------------------------------------------------------
extern "C" void kernel_launch(void* const* d_in, const int* in_sizes, int n_in,
                              void* d_out, int out_size, void* d_ws, size_t ws_size,
                              hipStream_t stream)
{
  (void)n_in; (void)out_size; (void)ws_size;
  const float* p   = (const float*)d_in[0];
  const float* x   = (const float*)d_in[1];
  const int*   knn = (const int*)  d_in[2];
  const float* W1  = (const float*)d_in[3];
  const float* Wv  = (const float*)d_in[4];
  const float* Wp1 = (const float*)d_in[5];
  const float* Wp2 = (const float*)d_in[6];
  const float* Ww  = (const float*)d_in[7];
  const float* W3  = (const float*)d_in[8];
  const float* g1  = (const float*)d_in[9];
  const float* b1  = (const float*)d_in[10];
  const float* g2  = (const float*)d_in[11];
  const float* b2  = (const float*)d_in[12];
  const float* g3  = (const float*)d_in[13];
  const float* b3  = (const float*)d_in[14];
  const int N = in_sizes[0] / 3;
  const float invN = 1.f / (float)N;

  u16* ws16 = (u16*)d_ws;
  u16* y16   = ws16;                       // N*64 f16 (y1, then y3)
  u16* v16   = y16 + (size_t)N*64;         // N*64 f16
  u16* mx16  = v16 + (size_t)N*64;         // N*64 f16
  u16* hw16  = mx16 + (size_t)N*64;        // N*8 f16
  uint4* fr  = (uint4*)(hw16 + (size_t)N*8);  // frag buffers (16B aligned)
  uint4* wwf  = fr;                        // 128 uint4
  uint4* wp2f = fr + 128;                  // 512 uint4
  uint4* w1f  = fr + 640;                  // 384 uint4
  float* partials = (float*)(fr + 1024);   // 128*PST f32
  float* ss1      = partials + (size_t)128*PST;
  float* ss2      = ss1 + 128;
  float* ss3      = ss2 + 128;

  pack_k<<<1, 256, 0, stream>>>(Wp2, Ww, Wp1, wwf, wp2f, w1f);
  gemm_mfma_k<0, false><<<GRID_GEMM, 256, 0, stream>>>(x, W1, nullptr, nullptr, y16, nullptr, partials, N);
  fin_k<<<64, 256, 0, stream>>>(partials, GRID_GEMM, g1, b1, ss1, invN);
  gemm_mfma_k<1, true><<<GRID_GEMM, 256, 0, stream>>>(y16, Wv, Ww, ss1, v16, hw16, nullptr, N);
  mixer_k<<<GRID_MIX, 256, 0, stream>>>(p, knn, v16, hw16, wwf, wp2f, w1f, mx16, partials, N);
  fin_k<<<64, 256, 0, stream>>>(partials, GRID_MIX, g2, b2, ss2, invN);
  gemm_mfma_k<2, true><<<GRID_GEMM, 256, 0, stream>>>(mx16, W3, nullptr, ss2, y16, nullptr, partials, N);
  fin_k<<<64, 256, 0, stream>>>(partials, GRID_GEMM, g3, b3, ss3, invN);
  final_k<<<GRID_ELT, 256, 0, stream>>>(y16, x, ss3, (float*)d_out, N*16);
}